// Round 11
// baseline (298.317 us; speedup 1.0000x reference)
//
#include <hip/hip_runtime.h>
#include <hip/hip_bf16.h>

#define SEQ   2048
#define BATCH 2
#define NROWS 4096
#define DM    1024
#define NHEAD 16
#define DH    64
#define QP    512
#define KVP   1024
#define CH    4      // key-tiles (of 64) per flash chunk (R11: 8->4 for 2x block parallelism)

typedef unsigned short us;
typedef ushort4 us4;
using bf16x8 = __attribute__((ext_vector_type(8))) __bf16;
using f32x4  = __attribute__((ext_vector_type(4))) float;

__device__ __forceinline__ us f2bf(float f) {
  union { __hip_bfloat16 h; us u; } cv;
  cv.h = __float2bfloat16(f);
  return cv.u;
}
__device__ __forceinline__ float bf2f(us u) {
  union { unsigned int u32; float f; } cv;
  cv.u32 = ((unsigned int)u) << 16;
  return cv.f;
}
__device__ __forceinline__ float loadp(const void* p, long i, int isbf) {
  return isbf ? bf2f(((const us*)p)[i]) : ((const float*)p)[i];
}
__device__ __forceinline__ void async16(const void* g, void* l) {
  __builtin_amdgcn_global_load_lds((__attribute__((address_space(1))) void*)g,
                                   (__attribute__((address_space(3))) void*)l,
                                   16, 0, 0);
}
// pack two f32 -> packed bf16 pair (RNE), single VALU op (no builtin on gfx950)
__device__ __forceinline__ unsigned cvtpk(float lo, float hi) {
  unsigned r;
  asm("v_cvt_pk_bf16_f32 %0, %1, %2" : "=v"(r) : "v"(lo), "v"(hi));
  return r;
}

// ---------------------------------------------------------------- dtype probe
// (fallback only -- host decides from in_sizes[0] when unambiguous)
__global__ void detect_dtype(const us* __restrict__ xu, int* __restrict__ flag) {
  __shared__ int red[256];
  const int tid = threadIdx.x;
  int cnt = 0;
  for (int i = tid; i < 4096; i += 256) {
    const int e = (xu[i] >> 7) & 0xff;
    if (e == 0 || (e >= 100 && e <= 134)) cnt++;
  }
  red[tid] = cnt;
  __syncthreads();
  for (int s = 128; s; s >>= 1) {
    if (tid < s) red[tid] += red[tid + s];
    __syncthreads();
  }
  if (tid == 0) *flag = (red[0] >= 3900) ? 1 : 0;
}

// ------------- stage0: weight prep (transpose/cast) + zero Oacc + dual-LN of x
struct TD { const void* in; us* out; int R, C, nt, trans; };

__global__ __launch_bounds__(256) void stage0(
    TD t0, TD t1, TD t2, TD t3, TD t4,
    float4* __restrict__ zp, int n4,                 // zero range (blocks 5120..6143)
    const void* __restrict__ xin,                    // ln_dual (blocks 6144..10239)
    const void* __restrict__ g1, const void* __restrict__ b1,
    const void* __restrict__ g2, const void* __restrict__ b2,
    us* __restrict__ out1, us* __restrict__ out2,
    const int* __restrict__ flag)
{
  __shared__ us tile[32][33];
  __shared__ float red[8];
  __shared__ float musd[2];
  const int tid = threadIdx.x;
  const int isbf = *flag;
  int lin = blockIdx.x;

  if (lin < 5120) {                                  // ---- weight prep
    TD t = t0;
    if (lin >= t.nt) { lin -= t.nt; t = t1;
      if (lin >= t.nt) { lin -= t.nt; t = t2;
        if (lin >= t.nt) { lin -= t.nt; t = t3;
          if (lin >= t.nt) { lin -= t.nt; t = t4; } } } }
    const int ntx = t.C >> 5;
    const int by = lin / ntx, bx = lin - by * ntx;
    const int tx = tid & 31, ty = tid >> 5;
    const long r0 = (long)by * 32, c0 = (long)bx * 32;
    if (t.trans) {
#pragma unroll
      for (int i = 0; i < 32; i += 8)
        tile[ty + i][tx] = isbf ? ((const us*)t.in)[(r0 + ty + i) * t.C + c0 + tx]
                                : f2bf(((const float*)t.in)[(r0 + ty + i) * t.C + c0 + tx]);
      __syncthreads();
#pragma unroll
      for (int i = 0; i < 32; i += 8)
        t.out[(c0 + ty + i) * t.R + r0 + tx] = tile[tx][ty + i];
    } else {
#pragma unroll
      for (int i = 0; i < 32; i += 8)
        t.out[(r0 + ty + i) * t.C + c0 + tx] =
            isbf ? ((const us*)t.in)[(r0 + ty + i) * t.C + c0 + tx]
                 : f2bf(((const float*)t.in)[(r0 + ty + i) * t.C + c0 + tx]);
    }
    return;
  }
  if (lin < 6144) {                                  // ---- zero Oacc/Lacc
    const float4 z = {0.f, 0.f, 0.f, 0.f};
    for (int i = (lin - 5120) * 256 + tid; i < n4; i += 1024 * 256) zp[i] = z;
    return;
  }
  // ---- dual LayerNorm row
  const long row = lin - 6144;
  float v[4];
  float s = 0.f, s2 = 0.f;
#pragma unroll
  for (int i = 0; i < 4; i++) {
    const long c = tid + i * 256;
    const float t = loadp(xin, row * 1024 + c, isbf);
    v[i] = t; s += t; s2 += t * t;
  }
#pragma unroll
  for (int off = 32; off > 0; off >>= 1) {
    s  += __shfl_down(s,  off);
    s2 += __shfl_down(s2, off);
  }
  const int wave = tid >> 6, lane = tid & 63;
  if (lane == 0) { red[wave] = s; red[4 + wave] = s2; }
  __syncthreads();
  if (tid == 0) {
    const float ts = red[0] + red[1] + red[2] + red[3];
    const float t2 = red[4] + red[5] + red[6] + red[7];
    const float mu = ts * (1.f / 1024.f);
    const float var = t2 * (1.f / 1024.f) - mu * mu;
    musd[0] = mu; musd[1] = rsqrtf(var + 1e-5f);
  }
  __syncthreads();
  const float mu = musd[0], rs = musd[1];
#pragma unroll
  for (int i = 0; i < 4; i++) {
    const long c = tid + i * 256;
    const float nrm = (v[i] - mu) * rs;
    out1[row * 1024 + c] = f2bf(nrm * loadp(g1, c, isbf) + loadp(b1, c, isbf));
    out2[row * 1024 + c] = f2bf(nrm * loadp(g2, c, isbf) + loadp(b2, c, isbf));
  }
}

// ------------------------------------------ paired row-LN (bf16 in -> bf16 out)
template<int C>
__device__ __forceinline__ void ln_body(const us* __restrict__ in,
                                        const void* __restrict__ g, const void* __restrict__ b,
                                        us* __restrict__ out, long row, int tid, int isbf) {
  constexpr int NP = C / 256;
  float v[NP];
  float s = 0.f, s2 = 0.f;
#pragma unroll
  for (int i = 0; i < NP; i++) {
    const float t = bf2f(in[row * C + tid + i * 256]);
    v[i] = t; s += t; s2 += t * t;
  }
#pragma unroll
  for (int off = 32; off > 0; off >>= 1) {
    s  += __shfl_down(s,  off);
    s2 += __shfl_down(s2, off);
  }
  __shared__ float red[8];
  __shared__ float musd[2];
  const int wave = tid >> 6, lane = tid & 63;
  if (lane == 0) { red[wave] = s; red[4 + wave] = s2; }
  __syncthreads();
  if (tid == 0) {
    const float ts = red[0] + red[1] + red[2] + red[3];
    const float t2 = red[4] + red[5] + red[6] + red[7];
    const float mu = ts * (1.f / C);
    const float var = t2 * (1.f / C) - mu * mu;
    musd[0] = mu; musd[1] = rsqrtf(var + 1e-5f);
  }
  __syncthreads();
  const float mu = musd[0], rs = musd[1];
#pragma unroll
  for (int i = 0; i < NP; i++) {
    const long c = tid + i * 256;
    out[row * C + c] = f2bf((v[i] - mu) * rs * loadp(g, c, isbf) + loadp(b, c, isbf));
  }
}

__global__ __launch_bounds__(256) void ln_rows_pair(
    const us* __restrict__ inq, const void* __restrict__ qg, const void* __restrict__ qb,
    us* __restrict__ outq,
    const us* __restrict__ inkv, const void* __restrict__ kvg, const void* __restrict__ kvb,
    us* __restrict__ outkv,
    const int* __restrict__ flag)
{
  const int isbf = *flag;
  if (blockIdx.x < NROWS)
    ln_body<512>(inq, qg, qb, outq, blockIdx.x, threadIdx.x, isbf);
  else
    ln_body<1024>(inkv, kvg, kvb, outkv, blockIdx.x - NROWS, threadIdx.x, isbf);
}

// ------------------------------------------------------------------ GEMM C = A @ B
// A [M,K] bf16, Bt [N,K] bf16 (= B^T), C [M,N]. 128x128 tile, BK=64 as two
// 32-wide LDS sub-slices (m97 layout preserved; barriers halved vs BK=32).
// omode: 0 = fp32 out, 1 = bf16 out, 2 = bf16 iff *flag.
// XCD swizzle (T1): consecutive logical tiles (sharing A-panels) pinned to one
// XCD's L2. All grids here are %8==0 -> simple bijective remap.
struct GD { const us* A; const us* Bt; void* C; int N, K, nxs; float scale; int omode; };

__global__ __launch_bounds__(256) void gemm_mt(GD g0, GD g1, int nb0,
                                               const int* __restrict__ flag) {
  __shared__ us As[2][128 * 32];
  __shared__ us Bs[2][128 * 32];
  GD g;
  int lin = blockIdx.x;
  {
    const int cpx = gridDim.x >> 3;        // gridDim.x % 8 == 0 for all launches
    lin = (lin & 7) * cpx + (lin >> 3);
  }
  if (lin < nb0) g = g0; else { g = g1; lin -= nb0; }
  const int by = lin >> g.nxs;
  const int bx = lin - (by << g.nxs);
  const int N = g.N, K = g.K;

  const int tid  = threadIdx.x;
  const int lane = tid & 63;
  const int wave = tid >> 6;
  const int n16  = lane & 15;
  const int quad = lane >> 4;
  const long m0 = (long)by * 128;
  const long n0 = (long)bx * 128;
  const int wm = (wave >> 1) * 64;
  const int wn = (wave & 1) * 64;

  const f32x4 zero = {0.f, 0.f, 0.f, 0.f};
  f32x4 acc[4][4];
#pragma unroll
  for (int i = 0; i < 4; i++)
#pragma unroll
    for (int j = 0; j < 4; j++) acc[i][j] = zero;

  const int srow = tid >> 2;
  const int scol = (tid & 3) * 8;
  const us* Ag0 = g.A  + (m0 + srow) * K + scol;
  const us* Ag1 = g.A  + (m0 + 64 + srow) * K + scol;
  const us* Bg0 = g.Bt + (n0 + srow) * K + scol;
  const us* Bg1 = g.Bt + (n0 + 64 + srow) * K + scol;
  const int lds_off = srow * 32 + scol;

  for (int k0 = 0; k0 < K; k0 += 64) {
#pragma unroll
    for (int s = 0; s < 2; s++) {
      const int ks = k0 + s * 32;
      async16(Ag0 + ks, As[s] + lds_off);
      async16(Ag1 + ks, As[s] + 2048 + lds_off);
      async16(Bg0 + ks, Bs[s] + lds_off);
      async16(Bg1 + ks, Bs[s] + 2048 + lds_off);
    }
    __syncthreads();
#pragma unroll
    for (int s = 0; s < 2; s++) {
      bf16x8 af[4], bfv[4];
#pragma unroll
      for (int i = 0; i < 4; i++)
        af[i] = *(const bf16x8*)(As[s] + (wm + i * 16 + n16) * 32 + quad * 8);
#pragma unroll
      for (int j = 0; j < 4; j++)
        bfv[j] = *(const bf16x8*)(Bs[s] + (wn + j * 16 + n16) * 32 + quad * 8);
#pragma unroll
      for (int i = 0; i < 4; i++)
#pragma unroll
        for (int j = 0; j < 4; j++)
          acc[i][j] = __builtin_amdgcn_mfma_f32_16x16x32_bf16(af[i], bfv[j], acc[i][j], 0, 0, 0);
    }
    __syncthreads();
  }

  const bool obf = (g.omode == 1) || (g.omode == 2 && *flag != 0);
  float* Cf = (float*)g.C;
  us* Cb = (us*)g.C;
#pragma unroll
  for (int i = 0; i < 4; i++) {
    const long row = m0 + wm + i * 16 + quad * 4;
#pragma unroll
    for (int j = 0; j < 4; j++) {
      const long col = n0 + wn + j * 16 + n16;
#pragma unroll
      for (int r = 0; r < 4; r++) {
        const float v = acc[i][j][r] * g.scale;
        if (obf) Cb[(row + r) * N + col] = f2bf(v);
        else     Cf[(row + r) * N + col] = v;
      }
    }
  }
}

// --------------------------------------------------- causal flash attention (split-K)
// Q pre-scaled by log2e/8 -> fixed-m softmax p = 2^s (scores O(1) for this problem).
// S^T = K·Q^T via swapped MFMA operands: lane holds 4 consecutive keys of ONE
// q-row.
//
// Key-slot remap: the MFMA contraction index over keys is an arbitrary
// permutation as long as the P (A) and V^T (B) fragments agree on it.
// QK^T leaves lane(n16,quad) holding P[key=16j+4*quad+r][qrow=n16]; choosing the
// PV contraction slot (kc,quad,t) -> key 32*kc + 16*(t>>2) + 4*quad + (t&3) makes
// the PV A-fragment exactly p[2kc+(t>>2)][t&3] -- lane-local, NO LDS round-trip.
// The V-transpose staging writes its 16 keys in this permuted column order.
//
// LDS: dense 64x64 tiles (8 KB each) with XOR swizzle SWZ -> conflict-free
// (verified 4.3M -> 0).
//
// R11: CH 8->4. Counters showed flash is neither BW-bound (1.1 TB/s) nor
// pipe-bound (MfmaUtil 12/VALU 29) but residency-limited (~2.8 blocks/CU of 8
// possible). Halving the chunk doubles block-level parallelism (grid 2560->4608,
// 18/CU) with ZERO change to per-wave register/LDS state (the register cliff
// that killed R1/R4). Cost: Oacc atomic writes ~2x (46->83 MB, well under BW).
//
// REGISTER CLIFF (measured twice): doubling per-wave state makes the allocator
// pick 32/64 regs + scratch spill (WRITE_SIZE 46->124/307 MB). Keep ~48-reg
// working set; launch bounds (256,4).
#define SWZ(row, col) ((row) * 64 + ((col) ^ (((row) & 7) << 3)))

__global__ __launch_bounds__(256, 4) void flash_attn(
    const us* __restrict__ Q, const us* __restrict__ KV,
    float* __restrict__ Oacc, float* __restrict__ Lacc)
{
  __shared__ us Ks[64 * 64];      // [key][dim], swizzled
  __shared__ us Vt[64 * 64];      // [dim][slot], swizzled (slot = permuted key)

  // decode (qt, chunk): qt descending -> longest-q first
  int lin = blockIdx.x;
  int qt = 31, nc = 0;
  for (; qt >= 0; --qt) { nc = (qt >> 2) + 1; if (lin < nc) break; lin -= nc; }
  const int chunk = lin;
  const int kt0 = chunk * CH;
  const int kt1 = min(kt0 + CH, qt + 1);

  const int h   = blockIdx.y;
  const int bb  = blockIdx.z;
  const int tid = threadIdx.x;
  const int lane = tid & 63;
  const int wave = tid >> 6;
  const int n16 = lane & 15;
  const int quad = lane >> 4;
  const int qbase = qt * 64;
  const long rowQ0 = (long)bb * SEQ;

  bf16x8 aq[2];
  {
    const long gq = (rowQ0 + qbase + wave * 16 + n16) * DM + h * DH;
    aq[0] = *(const bf16x8*)(Q + gq + quad * 8);
    aq[1] = *(const bf16x8*)(Q + gq + 32 + quad * 8);
  }

  const f32x4 zero = {0.f, 0.f, 0.f, 0.f};
  f32x4 oacc[4];
#pragma unroll
  for (int d = 0; d < 4; d++) oacc[d] = zero;
  float rsum = 0.f;                // row n16 partial sum

  const int kk_key = tid >> 3;
  const int kk_d8  = (tid & 7) * 8;
  const int vd  = tid & 63;
  const int vw  = tid >> 6;        // col block w: stores slots 8w..8w+7 (+32)
  const int vkb = vw * 8;

  const us* kgb = KV + (rowQ0 + kk_key) * 2048 + h * DH + kk_d8;
  // V source base at key 4w: lane (vd, w) loads keys {4w+r, 16+4w+r, 32+..., 48+...}
  const us* vgb = KV + (rowQ0 + vw * 4) * 2048 + KVP + h * DH + vd;

  uint4 kpre0, kpre1;
  us vraw[16];
  auto loadKV = [&](int kt) {
    const us* kg = kgb + (long)kt * (64 * 2048);
    kpre0 = *(const uint4*)kg;
    kpre1 = *(const uint4*)(kg + 32 * 2048);
    const us* vg = vgb + (long)kt * (64 * 2048);
#pragma unroll
    for (int r = 0; r < 4; r++) {
      vraw[r]      = vg[r * 2048];          // keys 4w + r        -> slots t=0..3 (kc=0)
      vraw[4 + r]  = vg[(16 + r) * 2048];   // keys 16 + 4w + r   -> slots t=4..7 (kc=0)
      vraw[8 + r]  = vg[(32 + r) * 2048];   // keys 32 + 4w + r   -> slots t=0..3 (kc=1)
      vraw[12 + r] = vg[(48 + r) * 2048];   // keys 48 + 4w + r   -> slots t=4..7 (kc=1)
    }
  };
  loadKV(kt0);

  for (int kt = kt0; kt < kt1; kt++) {
    __syncthreads();
    *(uint4*)(Ks + SWZ(kk_key, kk_d8))      = kpre0;
    *(uint4*)(Ks + SWZ(kk_key + 32, kk_d8)) = kpre1;
    {
      uint4 p0, p1;
      p0.x = (unsigned)vraw[0]  | ((unsigned)vraw[1]  << 16);
      p0.y = (unsigned)vraw[2]  | ((unsigned)vraw[3]  << 16);
      p0.z = (unsigned)vraw[4]  | ((unsigned)vraw[5]  << 16);
      p0.w = (unsigned)vraw[6]  | ((unsigned)vraw[7]  << 16);
      p1.x = (unsigned)vraw[8]  | ((unsigned)vraw[9]  << 16);
      p1.y = (unsigned)vraw[10] | ((unsigned)vraw[11] << 16);
      p1.z = (unsigned)vraw[12] | ((unsigned)vraw[13] << 16);
      p1.w = (unsigned)vraw[14] | ((unsigned)vraw[15] << 16);
      *(uint4*)(Vt + SWZ(vd, vkb))      = p0;   // kc=0 slots, col block w
      *(uint4*)(Vt + SWZ(vd, vkb + 32)) = p1;   // kc=1 slots
    }
    __syncthreads();
    if (kt + 1 < kt1) loadKV(kt + 1);

    // S^T = K Q^T: A = K-frag, B = aq. Lane holds S^T[key=j*16+quad*4+r][qrow=n16].
    f32x4 sv[4];
#pragma unroll
    for (int j = 0; j < 4; j++) {
      const bf16x8 ak0 = *(const bf16x8*)(Ks + SWZ(j * 16 + n16, quad * 8));
      const bf16x8 ak1 = *(const bf16x8*)(Ks + SWZ(j * 16 + n16, 32 + quad * 8));
      f32x4 s = zero;
      s = __builtin_amdgcn_mfma_f32_16x16x32_bf16(ak0, aq[0], s, 0, 0, 0);
      s = __builtin_amdgcn_mfma_f32_16x16x32_bf16(ak1, aq[1], s, 0, 0, 0);
      sv[j] = s;
    }

    // causal mask on the diagonal tile: key_local <= wave*16 + n16
    if (kt == qt) {
      const int qrl = wave * 16 + n16;
#pragma unroll
      for (int j = 0; j < 4; j++) {
        const int kl = j * 16 + quad * 4;
#pragma unroll
        for (int r = 0; r < 4; r++)
          sv[j][r] = (kl + r <= qrl) ? sv[j][r] : -1e30f;
      }
    }

    // p = 2^s, packed via v_cvt_pk_bf16_f32 (1 VALU op per pair vs ~6/elem sw RNE)
    unsigned pep[4][2];
#pragma unroll
    for (int j = 0; j < 4; j++) {
      const float p0 = __builtin_amdgcn_exp2f(sv[j][0]);
      const float p1 = __builtin_amdgcn_exp2f(sv[j][1]);
      const float p2 = __builtin_amdgcn_exp2f(sv[j][2]);
      const float p3 = __builtin_amdgcn_exp2f(sv[j][3]);
      rsum += (p0 + p1) + (p2 + p3);
      pep[j][0] = cvtpk(p0, p1);
      pep[j][1] = cvtpk(p2, p3);
    }

    // O += P V  (A = lane-local P slots, B = V^T[dim][slot]) -- no LDS round-trip
    __builtin_amdgcn_s_setprio(1);
#pragma unroll
    for (int kc = 0; kc < 2; kc++) {
      union { bf16x8 v; unsigned u[4]; } apu;
      apu.u[0] = pep[2 * kc][0];
      apu.u[1] = pep[2 * kc][1];
      apu.u[2] = pep[2 * kc + 1][0];
      apu.u[3] = pep[2 * kc + 1][1];
#pragma unroll
      for (int d = 0; d < 4; d++) {
        const bf16x8 bv = *(const bf16x8*)(Vt + SWZ(d * 16 + n16, kc * 32 + quad * 8));
        oacc[d] = __builtin_amdgcn_mfma_f32_16x16x32_bf16(apu.v, bv, oacc[d], 0, 0, 0);
      }
    }
    __builtin_amdgcn_s_setprio(0);
  }

  // row-sum reduce across quads (same n16 = same row)
  rsum += __shfl_xor(rsum, 16);
  rsum += __shfl_xor(rsum, 32);

  const long rw0 = rowQ0 + qbase + wave * 16;
  if (quad == 0)
    atomicAdd(&Lacc[(rw0 + n16) * NHEAD + h], rsum);
#pragma unroll
  for (int r = 0; r < 4; r++) {
    float* dst = Oacc + (rw0 + quad * 4 + r) * DM + h * DH + n16;
#pragma unroll
    for (int d = 0; d < 4; d++)
      atomicAdd(dst + d * 16, oacc[d][r]);
  }
}

// -------------------------------------------- combine: obuf = Oacc / l (bf16)
__global__ __launch_bounds__(256) void flash_combine(
    const float* __restrict__ Oacc, const float* __restrict__ Lacc,
    us* __restrict__ O)
{
  __shared__ float invl[NHEAD];
  const long row = blockIdx.x;
  const int tid = threadIdx.x;
  if (tid < NHEAD) invl[tid] = 1.f / Lacc[row * NHEAD + tid];
  __syncthreads();
#pragma unroll
  for (int i = 0; i < 4; i++) {
    const int col = tid + i * 256;
    O[row * DM + col] = f2bf(Oacc[row * DM + col] * invl[col >> 6]);
  }
}

// ------------------------------------------------------------------------- host
extern "C" void kernel_launch(void* const* d_in, const int* in_sizes, int n_in,
                              void* d_out, int out_size, void* d_ws, size_t ws_size,
                              hipStream_t stream) {
  const void* x      = d_in[0];
  const void* Wdq    = d_in[1];
  const void* Wuq    = d_in[2];
  const void* qg     = d_in[3];
  const void* qb     = d_in[4];
  const void* Wdkv   = d_in[5];
  const void* Wukv   = d_in[6];
  const void* kvg    = d_in[7];
  const void* kvb    = d_in[8];
  const void* preqg  = d_in[9];
  const void* preqb  = d_in[10];
  const void* prekvg = d_in[11];
  const void* prekvb = d_in[12];
  const void* wo     = d_in[13];

  char* ws = (char*)d_ws;
  const long MB = 1 << 20;
  int* flag   = (int*)ws;
  us* wdq_t   = (us*)(ws + 1 * MB);
  us* wuq_t   = (us*)(ws + 2 * MB);
  us* wdkv_t  = (us*)(ws + 3 * MB);
  us* wukv_t  = (us*)(ws + 5 * MB);
  us* wo_c    = (us*)(ws + 9 * MB);
  us* xq      = (us*)(ws + 11 * MB);                       // 8 MB
  us* xkv     = (us*)(ws + 19 * MB);                       // 8 MB
  float* Oacc = (float*)(ws + 27 * MB);                    // 16 MB (zeroed in stage0)
  float* Lacc = (float*)(ws + 43 * MB);                    // 256 KB
  us* obuf    = (us*)(ws + 43 * MB + 256 * 1024);          // 8 MB
  us* tq_bf   = obuf;                                      // overlay: dead before combine
  us* cq      = (us*)(ws + 43 * MB + 256 * 1024 + 8 * MB); // 4 MB
  us* qbuf    = (us*)(ws + 43 * MB + 256 * 1024 + 12 * MB);// 8 MB
  us* tkv_bf  = qbuf;                                      // overlay: dead before up-GEMM
  us* ckv     = (us*)(ws + 43 * MB + 256 * 1024 + 20 * MB);// 8 MB
  us* kv      = (us*)(ws + 43 * MB + 256 * 1024 + 28 * MB);// 16 MB -> ~87.25 MB total

  // dtype: decide host-side from x's byte size; probe only if ambiguous
  {
    static int hflag;
    const long xb = (long)in_sizes[0];
    int known = -1;
    if (xb == (long)BATCH * SEQ * DM * 4) known = 0;       // f32
    else if (xb == (long)BATCH * SEQ * DM * 2) known = 1;  // bf16
    if (known >= 0) {
      hflag = known;
      hipMemcpyAsync(flag, &hflag, sizeof(int), hipMemcpyHostToDevice, stream);
    } else {
      detect_dtype<<<1, 256, 0, stream>>>((const us*)x, flag);
    }
  }

  // stage0: weights (5120 blocks) + zero Oacc/Lacc (1024) + ln_dual (4096)
  {
    TD t0 = { Wdq,  wdq_t,  1024,  512,  512, 1 };
    TD t1 = { Wuq,  wuq_t,   512, 1024,  512, 1 };
    TD t2 = { Wdkv, wdkv_t, 1024, 1024, 1024, 1 };
    TD t3 = { Wukv, wukv_t, 1024, 2048, 2048, 1 };
    TD t4 = { wo,   wo_c,   1024, 1024, 1024, 0 };
    const int n4 = (16 * 1024 * 1024 + 256 * 1024) / 16;
    stage0<<<10240, 256, 0, stream>>>(t0, t1, t2, t3, t4,
                                      (float4*)Oacc, n4,
                                      x, preqg, preqb, prekvg, prekvb, xq, xkv, flag);
  }

  // down-projection pair (bf16 out)
  {
    GD g0 = { xq,  wdq_t,  tq_bf,   512, 1024, 2, 1.f, 1 };
    GD g1 = { xkv, wdkv_t, tkv_bf, 1024, 1024, 3, 1.f, 1 };
    gemm_mt<<<384, 256, 0, stream>>>(g0, g1, 128, flag);
  }

  ln_rows_pair<<<2 * NROWS, 256, 0, stream>>>(tq_bf, qg, qb, cq, tkv_bf, kvg, kvb, ckv, flag);

  // up-projection pair: Q scale = (1/8)*log2e for exp2-softmax
  {
    GD g0 = { cq,  wuq_t,  qbuf, 1024,  512, 3, 0.125f * 1.44269504f, 1 };
    GD g1 = { ckv, wukv_t, kv,   2048, 1024, 4, 1.f, 1 };
    gemm_mt<<<768, 256, 0, stream>>>(g0, g1, 256, flag);
  }

  // 144 chunks per (h,bb): sum over qt of (qt/4+1)
  flash_attn<<<dim3(144, NHEAD, BATCH), 256, 0, stream>>>(qbuf, kv, Oacc, Lacc);
  flash_combine<<<NROWS, 256, 0, stream>>>(Oacc, Lacc, obuf);

  // out = O @ wo^T
  {
    GD g0 = { obuf, wo_c, d_out, 1024, 1024, 3, 1.f, 2 };
    gemm_mt<<<256, 256, 0, stream>>>(g0, g0, 256, flag);
  }
}

// Round 12
// 263.590 us; speedup vs baseline: 1.1317x; 1.1317x over previous
//
#include <hip/hip_runtime.h>
#include <hip/hip_bf16.h>

#define SEQ   2048
#define BATCH 2
#define NROWS 4096
#define DM    1024
#define NHEAD 16
#define DH    64
#define QP    512
#define KVP   1024

typedef unsigned short us;
typedef ushort4 us4;
using bf16x8 = __attribute__((ext_vector_type(8))) __bf16;
using f32x4  = __attribute__((ext_vector_type(4))) float;

__device__ __forceinline__ us f2bf(float f) {
  union { __hip_bfloat16 h; us u; } cv;
  cv.h = __float2bfloat16(f);
  return cv.u;
}
__device__ __forceinline__ float bf2f(us u) {
  union { unsigned int u32; float f; } cv;
  cv.u32 = ((unsigned int)u) << 16;
  return cv.f;
}
__device__ __forceinline__ float loadp(const void* p, long i, int isbf) {
  return isbf ? bf2f(((const us*)p)[i]) : ((const float*)p)[i];
}
__device__ __forceinline__ void async16(const void* g, void* l) {
  __builtin_amdgcn_global_load_lds((__attribute__((address_space(1))) void*)g,
                                   (__attribute__((address_space(3))) void*)l,
                                   16, 0, 0);
}
// pack two f32 -> packed bf16 pair (RNE), single VALU op (no builtin on gfx950)
__device__ __forceinline__ unsigned cvtpk(float lo, float hi) {
  unsigned r;
  asm("v_cvt_pk_bf16_f32 %0, %1, %2" : "=v"(r) : "v"(lo), "v"(hi));
  return r;
}

// ---------------------------------------------------------------- dtype probe
// (fallback only -- host decides from in_sizes[0] when unambiguous)
__global__ void detect_dtype(const us* __restrict__ xu, int* __restrict__ flag) {
  __shared__ int red[256];
  const int tid = threadIdx.x;
  int cnt = 0;
  for (int i = tid; i < 4096; i += 256) {
    const int e = (xu[i] >> 7) & 0xff;
    if (e == 0 || (e >= 100 && e <= 134)) cnt++;
  }
  red[tid] = cnt;
  __syncthreads();
  for (int s = 128; s; s >>= 1) {
    if (tid < s) red[tid] += red[tid + s];
    __syncthreads();
  }
  if (tid == 0) *flag = (red[0] >= 3900) ? 1 : 0;
}

// ------------- stage0: weight prep (transpose/cast) + dual-LN of x
// (Oacc zeroing removed -- flash no longer uses a split-K accumulator)
struct TD { const void* in; us* out; int R, C, nt, trans; };

__global__ __launch_bounds__(256) void stage0(
    TD t0, TD t1, TD t2, TD t3, TD t4,
    const void* __restrict__ xin,                    // ln_dual (blocks 5120..9215)
    const void* __restrict__ g1, const void* __restrict__ b1,
    const void* __restrict__ g2, const void* __restrict__ b2,
    us* __restrict__ out1, us* __restrict__ out2,
    const int* __restrict__ flag)
{
  __shared__ us tile[32][33];
  __shared__ float red[8];
  __shared__ float musd[2];
  const int tid = threadIdx.x;
  const int isbf = *flag;
  int lin = blockIdx.x;

  if (lin < 5120) {                                  // ---- weight prep
    TD t = t0;
    if (lin >= t.nt) { lin -= t.nt; t = t1;
      if (lin >= t.nt) { lin -= t.nt; t = t2;
        if (lin >= t.nt) { lin -= t.nt; t = t3;
          if (lin >= t.nt) { lin -= t.nt; t = t4; } } } }
    const int ntx = t.C >> 5;
    const int by = lin / ntx, bx = lin - by * ntx;
    const int tx = tid & 31, ty = tid >> 5;
    const long r0 = (long)by * 32, c0 = (long)bx * 32;
    if (t.trans) {
#pragma unroll
      for (int i = 0; i < 32; i += 8)
        tile[ty + i][tx] = isbf ? ((const us*)t.in)[(r0 + ty + i) * t.C + c0 + tx]
                                : f2bf(((const float*)t.in)[(r0 + ty + i) * t.C + c0 + tx]);
      __syncthreads();
#pragma unroll
      for (int i = 0; i < 32; i += 8)
        t.out[(c0 + ty + i) * t.R + r0 + tx] = tile[tx][ty + i];
    } else {
#pragma unroll
      for (int i = 0; i < 32; i += 8)
        t.out[(r0 + ty + i) * t.C + c0 + tx] =
            isbf ? ((const us*)t.in)[(r0 + ty + i) * t.C + c0 + tx]
                 : f2bf(((const float*)t.in)[(r0 + ty + i) * t.C + c0 + tx]);
    }
    return;
  }
  // ---- dual LayerNorm row
  const long row = lin - 5120;
  float v[4];
  float s = 0.f, s2 = 0.f;
#pragma unroll
  for (int i = 0; i < 4; i++) {
    const long c = tid + i * 256;
    const float t = loadp(xin, row * 1024 + c, isbf);
    v[i] = t; s += t; s2 += t * t;
  }
#pragma unroll
  for (int off = 32; off > 0; off >>= 1) {
    s  += __shfl_down(s,  off);
    s2 += __shfl_down(s2, off);
  }
  const int wave = tid >> 6, lane = tid & 63;
  if (lane == 0) { red[wave] = s; red[4 + wave] = s2; }
  __syncthreads();
  if (tid == 0) {
    const float ts = red[0] + red[1] + red[2] + red[3];
    const float t2 = red[4] + red[5] + red[6] + red[7];
    const float mu = ts * (1.f / 1024.f);
    const float var = t2 * (1.f / 1024.f) - mu * mu;
    musd[0] = mu; musd[1] = rsqrtf(var + 1e-5f);
  }
  __syncthreads();
  const float mu = musd[0], rs = musd[1];
#pragma unroll
  for (int i = 0; i < 4; i++) {
    const long c = tid + i * 256;
    const float nrm = (v[i] - mu) * rs;
    out1[row * 1024 + c] = f2bf(nrm * loadp(g1, c, isbf) + loadp(b1, c, isbf));
    out2[row * 1024 + c] = f2bf(nrm * loadp(g2, c, isbf) + loadp(b2, c, isbf));
  }
}

// ------------------------------------------ paired row-LN (bf16 in -> bf16 out)
template<int C>
__device__ __forceinline__ void ln_body(const us* __restrict__ in,
                                        const void* __restrict__ g, const void* __restrict__ b,
                                        us* __restrict__ out, long row, int tid, int isbf) {
  constexpr int NP = C / 256;
  float v[NP];
  float s = 0.f, s2 = 0.f;
#pragma unroll
  for (int i = 0; i < NP; i++) {
    const float t = bf2f(in[row * C + tid + i * 256]);
    v[i] = t; s += t; s2 += t * t;
  }
#pragma unroll
  for (int off = 32; off > 0; off >>= 1) {
    s  += __shfl_down(s,  off);
    s2 += __shfl_down(s2, off);
  }
  __shared__ float red[8];
  __shared__ float musd[2];
  const int wave = tid >> 6, lane = tid & 63;
  if (lane == 0) { red[wave] = s; red[4 + wave] = s2; }
  __syncthreads();
  if (tid == 0) {
    const float ts = red[0] + red[1] + red[2] + red[3];
    const float t2 = red[4] + red[5] + red[6] + red[7];
    const float mu = ts * (1.f / C);
    const float var = t2 * (1.f / C) - mu * mu;
    musd[0] = mu; musd[1] = rsqrtf(var + 1e-5f);
  }
  __syncthreads();
  const float mu = musd[0], rs = musd[1];
#pragma unroll
  for (int i = 0; i < NP; i++) {
    const long c = tid + i * 256;
    out[row * C + c] = f2bf((v[i] - mu) * rs * loadp(g, c, isbf) + loadp(b, c, isbf));
  }
}

__global__ __launch_bounds__(256) void ln_rows_pair(
    const us* __restrict__ inq, const void* __restrict__ qg, const void* __restrict__ qb,
    us* __restrict__ outq,
    const us* __restrict__ inkv, const void* __restrict__ kvg, const void* __restrict__ kvb,
    us* __restrict__ outkv,
    const int* __restrict__ flag)
{
  const int isbf = *flag;
  if (blockIdx.x < NROWS)
    ln_body<512>(inq, qg, qb, outq, blockIdx.x, threadIdx.x, isbf);
  else
    ln_body<1024>(inkv, kvg, kvb, outkv, blockIdx.x - NROWS, threadIdx.x, isbf);
}

// ------------------------------------------------------------------ GEMM C = A @ B
// A [M,K] bf16, Bt [N,K] bf16 (= B^T), C [M,N]. 128x128 tile, BK=64 as two
// 32-wide LDS sub-slices (m97 layout preserved; barriers halved vs BK=32).
// omode: 0 = fp32 out, 1 = bf16 out, 2 = bf16 iff *flag.
// XCD swizzle (T1): consecutive logical tiles (sharing A-panels) pinned to one
// XCD's L2. All grids here are %8==0 -> simple bijective remap.
struct GD { const us* A; const us* Bt; void* C; int N, K, nxs; float scale; int omode; };

__global__ __launch_bounds__(256) void gemm_mt(GD g0, GD g1, int nb0,
                                               const int* __restrict__ flag) {
  __shared__ us As[2][128 * 32];
  __shared__ us Bs[2][128 * 32];
  GD g;
  int lin = blockIdx.x;
  {
    const int cpx = gridDim.x >> 3;        // gridDim.x % 8 == 0 for all launches
    lin = (lin & 7) * cpx + (lin >> 3);
  }
  if (lin < nb0) g = g0; else { g = g1; lin -= nb0; }
  const int by = lin >> g.nxs;
  const int bx = lin - (by << g.nxs);
  const int N = g.N, K = g.K;

  const int tid  = threadIdx.x;
  const int lane = tid & 63;
  const int wave = tid >> 6;
  const int n16  = lane & 15;
  const int quad = lane >> 4;
  const long m0 = (long)by * 128;
  const long n0 = (long)bx * 128;
  const int wm = (wave >> 1) * 64;
  const int wn = (wave & 1) * 64;

  const f32x4 zero = {0.f, 0.f, 0.f, 0.f};
  f32x4 acc[4][4];
#pragma unroll
  for (int i = 0; i < 4; i++)
#pragma unroll
    for (int j = 0; j < 4; j++) acc[i][j] = zero;

  const int srow = tid >> 2;
  const int scol = (tid & 3) * 8;
  const us* Ag0 = g.A  + (m0 + srow) * K + scol;
  const us* Ag1 = g.A  + (m0 + 64 + srow) * K + scol;
  const us* Bg0 = g.Bt + (n0 + srow) * K + scol;
  const us* Bg1 = g.Bt + (n0 + 64 + srow) * K + scol;
  const int lds_off = srow * 32 + scol;

  for (int k0 = 0; k0 < K; k0 += 64) {
#pragma unroll
    for (int s = 0; s < 2; s++) {
      const int ks = k0 + s * 32;
      async16(Ag0 + ks, As[s] + lds_off);
      async16(Ag1 + ks, As[s] + 2048 + lds_off);
      async16(Bg0 + ks, Bs[s] + lds_off);
      async16(Bg1 + ks, Bs[s] + 2048 + lds_off);
    }
    __syncthreads();
#pragma unroll
    for (int s = 0; s < 2; s++) {
      bf16x8 af[4], bfv[4];
#pragma unroll
      for (int i = 0; i < 4; i++)
        af[i] = *(const bf16x8*)(As[s] + (wm + i * 16 + n16) * 32 + quad * 8);
#pragma unroll
      for (int j = 0; j < 4; j++)
        bfv[j] = *(const bf16x8*)(Bs[s] + (wn + j * 16 + n16) * 32 + quad * 8);
#pragma unroll
      for (int i = 0; i < 4; i++)
#pragma unroll
        for (int j = 0; j < 4; j++)
          acc[i][j] = __builtin_amdgcn_mfma_f32_16x16x32_bf16(af[i], bfv[j], acc[i][j], 0, 0, 0);
    }
    __syncthreads();
  }

  const bool obf = (g.omode == 1) || (g.omode == 2 && *flag != 0);
  float* Cf = (float*)g.C;
  us* Cb = (us*)g.C;
#pragma unroll
  for (int i = 0; i < 4; i++) {
    const long row = m0 + wm + i * 16 + quad * 4;
#pragma unroll
    for (int j = 0; j < 4; j++) {
      const long col = n0 + wn + j * 16 + n16;
#pragma unroll
      for (int r = 0; r < 4; r++) {
        const float v = acc[i][j][r] * g.scale;
        if (obf) Cb[(row + r) * N + col] = f2bf(v);
        else     Cf[(row + r) * N + col] = v;
      }
    }
  }
}

// --------------------------------------------------- causal flash attention
// R12: NO split-K. R11's CH=4 experiment exposed the real limiter: the split-K
// f32 atomic accumulation ran at a constant ~210 G atomics/s in BOTH R10
// (10.5M atomics / 52 us) and R11 (18.9M / 85 us) -- flash was atomic-
// throughput-bound all along (explains insensitivity to LDS/barriers/dbuf).
// Now ONE block owns one (q-tile, head, batch): grid (32,16,2), qt = 31 -
// blockIdx.x (longest blocks dispatch first), kt = 0..qt. rsum is the FULL
// softmax denominator -> divide in-kernel, plain bf16 stores to O. Deleted:
// Oacc+Lacc (24 MB traffic), the 16 MB zeroing, and the flash_combine pass.
//
// Q pre-scaled by log2e/8 -> fixed-m softmax p = 2^s. S^T = K.Q^T via swapped
// operands; key-slot remap (PV contraction slot (kc,quad,t) -> key
// 32*kc + 16*(t>>2) + 4*quad + (t&3)) keeps the PV A-fragment lane-local.
// LDS: dense 64x64 XOR-swizzled tiles (conflict-free, verified 4.3M -> 0).
// REGISTER CLIFF: keep ~48-reg working set (R1/R4 spills); bounds (256,4).
#define SWZ(row, col) ((row) * 64 + ((col) ^ (((row) & 7) << 3)))

__global__ __launch_bounds__(256, 4) void flash_attn(
    const us* __restrict__ Q, const us* __restrict__ KV,
    us* __restrict__ O)
{
  __shared__ us Ks[64 * 64];      // [key][dim], swizzled
  __shared__ us Vt[64 * 64];      // [dim][slot], swizzled (slot = permuted key)

  const int qt = 31 - (int)blockIdx.x;   // longest-q first
  const int nt = qt + 1;

  const int h   = blockIdx.y;
  const int bb  = blockIdx.z;
  const int tid = threadIdx.x;
  const int lane = tid & 63;
  const int wave = tid >> 6;
  const int n16 = lane & 15;
  const int quad = lane >> 4;
  const int qbase = qt * 64;
  const long rowQ0 = (long)bb * SEQ;

  bf16x8 aq[2];
  {
    const long gq = (rowQ0 + qbase + wave * 16 + n16) * DM + h * DH;
    aq[0] = *(const bf16x8*)(Q + gq + quad * 8);
    aq[1] = *(const bf16x8*)(Q + gq + 32 + quad * 8);
  }

  const f32x4 zero = {0.f, 0.f, 0.f, 0.f};
  f32x4 oacc[4];
#pragma unroll
  for (int d = 0; d < 4; d++) oacc[d] = zero;
  float rsum = 0.f;                // row n16 partial sum

  const int kk_key = tid >> 3;
  const int kk_d8  = (tid & 7) * 8;
  const int vd  = tid & 63;
  const int vw  = tid >> 6;        // col block w: stores slots 8w..8w+7 (+32)
  const int vkb = vw * 8;

  const us* kgb = KV + (rowQ0 + kk_key) * 2048 + h * DH + kk_d8;
  // V source base at key 4w: lane (vd, w) loads keys {4w+r, 16+4w+r, 32+..., 48+...}
  const us* vgb = KV + (rowQ0 + vw * 4) * 2048 + KVP + h * DH + vd;

  uint4 kpre0, kpre1;
  us vraw[16];
  auto loadKV = [&](int kt) {
    const us* kg = kgb + (long)kt * (64 * 2048);
    kpre0 = *(const uint4*)kg;
    kpre1 = *(const uint4*)(kg + 32 * 2048);
    const us* vg = vgb + (long)kt * (64 * 2048);
#pragma unroll
    for (int r = 0; r < 4; r++) {
      vraw[r]      = vg[r * 2048];          // keys 4w + r        -> slots t=0..3 (kc=0)
      vraw[4 + r]  = vg[(16 + r) * 2048];   // keys 16 + 4w + r   -> slots t=4..7 (kc=0)
      vraw[8 + r]  = vg[(32 + r) * 2048];   // keys 32 + 4w + r   -> slots t=0..3 (kc=1)
      vraw[12 + r] = vg[(48 + r) * 2048];   // keys 48 + 4w + r   -> slots t=4..7 (kc=1)
    }
  };
  loadKV(0);

  for (int kt = 0; kt < nt; kt++) {
    __syncthreads();
    *(uint4*)(Ks + SWZ(kk_key, kk_d8))      = kpre0;
    *(uint4*)(Ks + SWZ(kk_key + 32, kk_d8)) = kpre1;
    {
      uint4 p0, p1;
      p0.x = (unsigned)vraw[0]  | ((unsigned)vraw[1]  << 16);
      p0.y = (unsigned)vraw[2]  | ((unsigned)vraw[3]  << 16);
      p0.z = (unsigned)vraw[4]  | ((unsigned)vraw[5]  << 16);
      p0.w = (unsigned)vraw[6]  | ((unsigned)vraw[7]  << 16);
      p1.x = (unsigned)vraw[8]  | ((unsigned)vraw[9]  << 16);
      p1.y = (unsigned)vraw[10] | ((unsigned)vraw[11] << 16);
      p1.z = (unsigned)vraw[12] | ((unsigned)vraw[13] << 16);
      p1.w = (unsigned)vraw[14] | ((unsigned)vraw[15] << 16);
      *(uint4*)(Vt + SWZ(vd, vkb))      = p0;   // kc=0 slots, col block w
      *(uint4*)(Vt + SWZ(vd, vkb + 32)) = p1;   // kc=1 slots
    }
    __syncthreads();
    if (kt + 1 < nt) loadKV(kt + 1);

    // S^T = K Q^T: A = K-frag, B = aq. Lane holds S^T[key=j*16+quad*4+r][qrow=n16].
    f32x4 sv[4];
#pragma unroll
    for (int j = 0; j < 4; j++) {
      const bf16x8 ak0 = *(const bf16x8*)(Ks + SWZ(j * 16 + n16, quad * 8));
      const bf16x8 ak1 = *(const bf16x8*)(Ks + SWZ(j * 16 + n16, 32 + quad * 8));
      f32x4 s = zero;
      s = __builtin_amdgcn_mfma_f32_16x16x32_bf16(ak0, aq[0], s, 0, 0, 0);
      s = __builtin_amdgcn_mfma_f32_16x16x32_bf16(ak1, aq[1], s, 0, 0, 0);
      sv[j] = s;
    }

    // causal mask on the diagonal tile: key_local <= wave*16 + n16
    if (kt == qt) {
      const int qrl = wave * 16 + n16;
#pragma unroll
      for (int j = 0; j < 4; j++) {
        const int kl = j * 16 + quad * 4;
#pragma unroll
        for (int r = 0; r < 4; r++)
          sv[j][r] = (kl + r <= qrl) ? sv[j][r] : -1e30f;
      }
    }

    // p = 2^s, packed via v_cvt_pk_bf16_f32 (1 VALU op per pair vs ~6/elem sw RNE)
    unsigned pep[4][2];
#pragma unroll
    for (int j = 0; j < 4; j++) {
      const float p0 = __builtin_amdgcn_exp2f(sv[j][0]);
      const float p1 = __builtin_amdgcn_exp2f(sv[j][1]);
      const float p2 = __builtin_amdgcn_exp2f(sv[j][2]);
      const float p3 = __builtin_amdgcn_exp2f(sv[j][3]);
      rsum += (p0 + p1) + (p2 + p3);
      pep[j][0] = cvtpk(p0, p1);
      pep[j][1] = cvtpk(p2, p3);
    }

    // O += P V  (A = lane-local P slots, B = V^T[dim][slot]) -- no LDS round-trip
    __builtin_amdgcn_s_setprio(1);
#pragma unroll
    for (int kc = 0; kc < 2; kc++) {
      union { bf16x8 v; unsigned u[4]; } apu;
      apu.u[0] = pep[2 * kc][0];
      apu.u[1] = pep[2 * kc][1];
      apu.u[2] = pep[2 * kc + 1][0];
      apu.u[3] = pep[2 * kc + 1][1];
#pragma unroll
      for (int d = 0; d < 4; d++) {
        const bf16x8 bv = *(const bf16x8*)(Vt + SWZ(d * 16 + n16, kc * 32 + quad * 8));
        oacc[d] = __builtin_amdgcn_mfma_f32_16x16x32_bf16(apu.v, bv, oacc[d], 0, 0, 0);
      }
    }
    __builtin_amdgcn_s_setprio(0);
  }

  // full softmax denominator for q-row n16 (all keys live in this block)
  rsum += __shfl_xor(rsum, 16);
  rsum += __shfl_xor(rsum, 32);
  const float inv = 1.f / rsum;

  // oacc[d][r] belongs to q-row quad*4+r, dim d*16+n16; fetch that row's inv
  // from the lane holding it (lane quad*4+r, quad'=0) and store bf16 directly.
  const long rw0 = rowQ0 + qbase + wave * 16;
#pragma unroll
  for (int r = 0; r < 4; r++) {
    const float invr = __shfl(inv, quad * 4 + r);
    us* dst = O + (rw0 + quad * 4 + r) * DM + h * DH + n16;
#pragma unroll
    for (int d = 0; d < 4; d++)
      dst[d * 16] = f2bf(oacc[d][r] * invr);
  }
}

// ------------------------------------------------------------------------- host
extern "C" void kernel_launch(void* const* d_in, const int* in_sizes, int n_in,
                              void* d_out, int out_size, void* d_ws, size_t ws_size,
                              hipStream_t stream) {
  const void* x      = d_in[0];
  const void* Wdq    = d_in[1];
  const void* Wuq    = d_in[2];
  const void* qg     = d_in[3];
  const void* qb     = d_in[4];
  const void* Wdkv   = d_in[5];
  const void* Wukv   = d_in[6];
  const void* kvg    = d_in[7];
  const void* kvb    = d_in[8];
  const void* preqg  = d_in[9];
  const void* preqb  = d_in[10];
  const void* prekvg = d_in[11];
  const void* prekvb = d_in[12];
  const void* wo     = d_in[13];

  char* ws = (char*)d_ws;
  const long MB = 1 << 20;
  int* flag   = (int*)ws;
  us* wdq_t   = (us*)(ws + 1 * MB);
  us* wuq_t   = (us*)(ws + 2 * MB);
  us* wdkv_t  = (us*)(ws + 3 * MB);
  us* wukv_t  = (us*)(ws + 5 * MB);
  us* wo_c    = (us*)(ws + 9 * MB);
  us* xq      = (us*)(ws + 11 * MB);                       // 8 MB
  us* xkv     = (us*)(ws + 19 * MB);                       // 8 MB
  us* obuf    = (us*)(ws + 27 * MB);                       // 8 MB (flash output)
  us* tq_bf   = obuf;                                      // overlay: tq dead before flash writes obuf
  us* cq      = (us*)(ws + 35 * MB);                       // 4 MB
  us* qbuf    = (us*)(ws + 39 * MB);                       // 8 MB
  us* tkv_bf  = qbuf;                                      // overlay: dead before up-GEMM
  us* ckv     = (us*)(ws + 47 * MB);                       // 8 MB
  us* kv      = (us*)(ws + 55 * MB);                       // 16 MB -> 71 MB total

  // dtype: decide host-side from x's byte size; probe only if ambiguous
  {
    static int hflag;
    const long xb = (long)in_sizes[0];
    int known = -1;
    if (xb == (long)BATCH * SEQ * DM * 4) known = 0;       // f32
    else if (xb == (long)BATCH * SEQ * DM * 2) known = 1;  // bf16
    if (known >= 0) {
      hflag = known;
      hipMemcpyAsync(flag, &hflag, sizeof(int), hipMemcpyHostToDevice, stream);
    } else {
      detect_dtype<<<1, 256, 0, stream>>>((const us*)x, flag);
    }
  }

  // stage0: weights (5120 blocks) + ln_dual (4096) -- zeroing removed
  {
    TD t0 = { Wdq,  wdq_t,  1024,  512,  512, 1 };
    TD t1 = { Wuq,  wuq_t,   512, 1024,  512, 1 };
    TD t2 = { Wdkv, wdkv_t, 1024, 1024, 1024, 1 };
    TD t3 = { Wukv, wukv_t, 1024, 2048, 2048, 1 };
    TD t4 = { wo,   wo_c,   1024, 1024, 1024, 0 };
    stage0<<<9216, 256, 0, stream>>>(t0, t1, t2, t3, t4,
                                     x, preqg, preqb, prekvg, prekvb, xq, xkv, flag);
  }

  // down-projection pair (bf16 out)
  {
    GD g0 = { xq,  wdq_t,  tq_bf,   512, 1024, 2, 1.f, 1 };
    GD g1 = { xkv, wdkv_t, tkv_bf, 1024, 1024, 3, 1.f, 1 };
    gemm_mt<<<384, 256, 0, stream>>>(g0, g1, 128, flag);
  }

  ln_rows_pair<<<2 * NROWS, 256, 0, stream>>>(tq_bf, qg, qb, cq, tkv_bf, kvg, kvb, ckv, flag);

  // up-projection pair: Q scale = (1/8)*log2e for exp2-softmax
  {
    GD g0 = { cq,  wuq_t,  qbuf, 1024,  512, 3, 0.125f * 1.44269504f, 1 };
    GD g1 = { ckv, wukv_t, kv,   2048, 1024, 4, 1.f, 1 };
    gemm_mt<<<768, 256, 0, stream>>>(g0, g1, 256, flag);
  }

  // one block per (q-tile, head, batch); longest q-tiles dispatch first
  flash_attn<<<dim3(32, NHEAD, BATCH), 256, 0, stream>>>(qbuf, kv, obuf);

  // out = O @ wo^T
  {
    GD g0 = { obuf, wo_c, d_out, 1024, 1024, 3, 1.f, 2 };
    gemm_mt<<<256, 256, 0, stream>>>(g0, g0, 256, flag);
  }
}

// Round 13
// 257.947 us; speedup vs baseline: 1.1565x; 1.0219x over previous
//
#include <hip/hip_runtime.h>
#include <hip/hip_bf16.h>

#define SEQ   2048
#define BATCH 2
#define NROWS 4096
#define DM    1024
#define NHEAD 16
#define DH    64
#define QP    512
#define KVP   1024

typedef unsigned short us;
typedef ushort4 us4;
using bf16x8 = __attribute__((ext_vector_type(8))) __bf16;
using f32x4  = __attribute__((ext_vector_type(4))) float;

__device__ __forceinline__ us f2bf(float f) {
  union { __hip_bfloat16 h; us u; } cv;
  cv.h = __float2bfloat16(f);
  return cv.u;
}
__device__ __forceinline__ float bf2f(us u) {
  union { unsigned int u32; float f; } cv;
  cv.u32 = ((unsigned int)u) << 16;
  return cv.f;
}
__device__ __forceinline__ float loadp(const void* p, long i, int isbf) {
  return isbf ? bf2f(((const us*)p)[i]) : ((const float*)p)[i];
}
__device__ __forceinline__ void async16(const void* g, void* l) {
  __builtin_amdgcn_global_load_lds((__attribute__((address_space(1))) void*)g,
                                   (__attribute__((address_space(3))) void*)l,
                                   16, 0, 0);
}
// pack two f32 -> packed bf16 pair (RNE), single VALU op (no builtin on gfx950)
__device__ __forceinline__ unsigned cvtpk(float lo, float hi) {
  unsigned r;
  asm("v_cvt_pk_bf16_f32 %0, %1, %2" : "=v"(r) : "v"(lo), "v"(hi));
  return r;
}

// ---------------------------------------------------------------- dtype probe
// (fallback only -- host decides from in_sizes[0] when unambiguous)
__global__ void detect_dtype(const us* __restrict__ xu, int* __restrict__ flag) {
  __shared__ int red[256];
  const int tid = threadIdx.x;
  int cnt = 0;
  for (int i = tid; i < 4096; i += 256) {
    const int e = (xu[i] >> 7) & 0xff;
    if (e == 0 || (e >= 100 && e <= 134)) cnt++;
  }
  red[tid] = cnt;
  __syncthreads();
  for (int s = 128; s; s >>= 1) {
    if (tid < s) red[tid] += red[tid + s];
    __syncthreads();
  }
  if (tid == 0) *flag = (red[0] >= 3900) ? 1 : 0;
}

// ------------- stage0: weight prep (transpose/cast) + dual-LN of x
struct TD { const void* in; us* out; int R, C, nt, trans; };

__global__ __launch_bounds__(256) void stage0(
    TD t0, TD t1, TD t2, TD t3, TD t4,
    const void* __restrict__ xin,                    // ln_dual (blocks 5120..9215)
    const void* __restrict__ g1, const void* __restrict__ b1,
    const void* __restrict__ g2, const void* __restrict__ b2,
    us* __restrict__ out1, us* __restrict__ out2,
    const int* __restrict__ flag)
{
  __shared__ us tile[32][33];
  __shared__ float red[8];
  __shared__ float musd[2];
  const int tid = threadIdx.x;
  const int isbf = *flag;
  int lin = blockIdx.x;

  if (lin < 5120) {                                  // ---- weight prep
    TD t = t0;
    if (lin >= t.nt) { lin -= t.nt; t = t1;
      if (lin >= t.nt) { lin -= t.nt; t = t2;
        if (lin >= t.nt) { lin -= t.nt; t = t3;
          if (lin >= t.nt) { lin -= t.nt; t = t4; } } } }
    const int ntx = t.C >> 5;
    const int by = lin / ntx, bx = lin - by * ntx;
    const int tx = tid & 31, ty = tid >> 5;
    const long r0 = (long)by * 32, c0 = (long)bx * 32;
    if (t.trans) {
#pragma unroll
      for (int i = 0; i < 32; i += 8)
        tile[ty + i][tx] = isbf ? ((const us*)t.in)[(r0 + ty + i) * t.C + c0 + tx]
                                : f2bf(((const float*)t.in)[(r0 + ty + i) * t.C + c0 + tx]);
      __syncthreads();
#pragma unroll
      for (int i = 0; i < 32; i += 8)
        t.out[(c0 + ty + i) * t.R + r0 + tx] = tile[tx][ty + i];
    } else {
#pragma unroll
      for (int i = 0; i < 32; i += 8)
        t.out[(r0 + ty + i) * t.C + c0 + tx] =
            isbf ? ((const us*)t.in)[(r0 + ty + i) * t.C + c0 + tx]
                 : f2bf(((const float*)t.in)[(r0 + ty + i) * t.C + c0 + tx]);
    }
    return;
  }
  // ---- dual LayerNorm row
  const long row = lin - 5120;
  float v[4];
  float s = 0.f, s2 = 0.f;
#pragma unroll
  for (int i = 0; i < 4; i++) {
    const long c = tid + i * 256;
    const float t = loadp(xin, row * 1024 + c, isbf);
    v[i] = t; s += t; s2 += t * t;
  }
#pragma unroll
  for (int off = 32; off > 0; off >>= 1) {
    s  += __shfl_down(s,  off);
    s2 += __shfl_down(s2, off);
  }
  const int wave = tid >> 6, lane = tid & 63;
  if (lane == 0) { red[wave] = s; red[4 + wave] = s2; }
  __syncthreads();
  if (tid == 0) {
    const float ts = red[0] + red[1] + red[2] + red[3];
    const float t2 = red[4] + red[5] + red[6] + red[7];
    const float mu = ts * (1.f / 1024.f);
    const float var = t2 * (1.f / 1024.f) - mu * mu;
    musd[0] = mu; musd[1] = rsqrtf(var + 1e-5f);
  }
  __syncthreads();
  const float mu = musd[0], rs = musd[1];
#pragma unroll
  for (int i = 0; i < 4; i++) {
    const long c = tid + i * 256;
    const float nrm = (v[i] - mu) * rs;
    out1[row * 1024 + c] = f2bf(nrm * loadp(g1, c, isbf) + loadp(b1, c, isbf));
    out2[row * 1024 + c] = f2bf(nrm * loadp(g2, c, isbf) + loadp(b2, c, isbf));
  }
}

// ------------------------------------------ paired row-LN (bf16 in -> bf16 out)
template<int C>
__device__ __forceinline__ void ln_body(const us* __restrict__ in,
                                        const void* __restrict__ g, const void* __restrict__ b,
                                        us* __restrict__ out, long row, int tid, int isbf) {
  constexpr int NP = C / 256;
  float v[NP];
  float s = 0.f, s2 = 0.f;
#pragma unroll
  for (int i = 0; i < NP; i++) {
    const float t = bf2f(in[row * C + tid + i * 256]);
    v[i] = t; s += t; s2 += t * t;
  }
#pragma unroll
  for (int off = 32; off > 0; off >>= 1) {
    s  += __shfl_down(s,  off);
    s2 += __shfl_down(s2, off);
  }
  __shared__ float red[8];
  __shared__ float musd[2];
  const int wave = tid >> 6, lane = tid & 63;
  if (lane == 0) { red[wave] = s; red[4 + wave] = s2; }
  __syncthreads();
  if (tid == 0) {
    const float ts = red[0] + red[1] + red[2] + red[3];
    const float t2 = red[4] + red[5] + red[6] + red[7];
    const float mu = ts * (1.f / C);
    const float var = t2 * (1.f / C) - mu * mu;
    musd[0] = mu; musd[1] = rsqrtf(var + 1e-5f);
  }
  __syncthreads();
  const float mu = musd[0], rs = musd[1];
#pragma unroll
  for (int i = 0; i < NP; i++) {
    const long c = tid + i * 256;
    out[row * C + c] = f2bf((v[i] - mu) * rs * loadp(g, c, isbf) + loadp(b, c, isbf));
  }
}

__global__ __launch_bounds__(256) void ln_rows_pair(
    const us* __restrict__ inq, const void* __restrict__ qg, const void* __restrict__ qb,
    us* __restrict__ outq,
    const us* __restrict__ inkv, const void* __restrict__ kvg, const void* __restrict__ kvb,
    us* __restrict__ outkv,
    const int* __restrict__ flag)
{
  const int isbf = *flag;
  if (blockIdx.x < NROWS)
    ln_body<512>(inq, qg, qb, outq, blockIdx.x, threadIdx.x, isbf);
  else
    ln_body<1024>(inkv, kvg, kvb, outkv, blockIdx.x - NROWS, threadIdx.x, isbf);
}

// ------------------------------------------------------------------ GEMM C = A @ B
// A [M,K] bf16, Bt [N,K] bf16 (= B^T), C [M,N]. 128x128 tile, BK=64 as two
// 32-wide LDS sub-slices (m97 layout preserved; barriers halved vs BK=32).
// omode: 0 = fp32 out, 1 = bf16 out, 2 = bf16 iff *flag.
// XCD swizzle (T1): consecutive logical tiles (sharing A-panels) pinned to one
// XCD's L2. All grids here are %8==0 -> simple bijective remap.
struct GD { const us* A; const us* Bt; void* C; int N, K, nxs; float scale; int omode; };

__global__ __launch_bounds__(256) void gemm_mt(GD g0, GD g1, int nb0,
                                               const int* __restrict__ flag) {
  __shared__ us As[2][128 * 32];
  __shared__ us Bs[2][128 * 32];
  GD g;
  int lin = blockIdx.x;
  {
    const int cpx = gridDim.x >> 3;        // gridDim.x % 8 == 0 for all launches
    lin = (lin & 7) * cpx + (lin >> 3);
  }
  if (lin < nb0) g = g0; else { g = g1; lin -= nb0; }
  const int by = lin >> g.nxs;
  const int bx = lin - (by << g.nxs);
  const int N = g.N, K = g.K;

  const int tid  = threadIdx.x;
  const int lane = tid & 63;
  const int wave = tid >> 6;
  const int n16  = lane & 15;
  const int quad = lane >> 4;
  const long m0 = (long)by * 128;
  const long n0 = (long)bx * 128;
  const int wm = (wave >> 1) * 64;
  const int wn = (wave & 1) * 64;

  const f32x4 zero = {0.f, 0.f, 0.f, 0.f};
  f32x4 acc[4][4];
#pragma unroll
  for (int i = 0; i < 4; i++)
#pragma unroll
    for (int j = 0; j < 4; j++) acc[i][j] = zero;

  const int srow = tid >> 2;
  const int scol = (tid & 3) * 8;
  const us* Ag0 = g.A  + (m0 + srow) * K + scol;
  const us* Ag1 = g.A  + (m0 + 64 + srow) * K + scol;
  const us* Bg0 = g.Bt + (n0 + srow) * K + scol;
  const us* Bg1 = g.Bt + (n0 + 64 + srow) * K + scol;
  const int lds_off = srow * 32 + scol;

  for (int k0 = 0; k0 < K; k0 += 64) {
#pragma unroll
    for (int s = 0; s < 2; s++) {
      const int ks = k0 + s * 32;
      async16(Ag0 + ks, As[s] + lds_off);
      async16(Ag1 + ks, As[s] + 2048 + lds_off);
      async16(Bg0 + ks, Bs[s] + lds_off);
      async16(Bg1 + ks, Bs[s] + 2048 + lds_off);
    }
    __syncthreads();
#pragma unroll
    for (int s = 0; s < 2; s++) {
      bf16x8 af[4], bfv[4];
#pragma unroll
      for (int i = 0; i < 4; i++)
        af[i] = *(const bf16x8*)(As[s] + (wm + i * 16 + n16) * 32 + quad * 8);
#pragma unroll
      for (int j = 0; j < 4; j++)
        bfv[j] = *(const bf16x8*)(Bs[s] + (wn + j * 16 + n16) * 32 + quad * 8);
#pragma unroll
      for (int i = 0; i < 4; i++)
#pragma unroll
        for (int j = 0; j < 4; j++)
          acc[i][j] = __builtin_amdgcn_mfma_f32_16x16x32_bf16(af[i], bfv[j], acc[i][j], 0, 0, 0);
    }
    __syncthreads();
  }

  const bool obf = (g.omode == 1) || (g.omode == 2 && *flag != 0);
  float* Cf = (float*)g.C;
  us* Cb = (us*)g.C;
#pragma unroll
  for (int i = 0; i < 4; i++) {
    const long row = m0 + wm + i * 16 + quad * 4;
#pragma unroll
    for (int j = 0; j < 4; j++) {
      const long col = n0 + wn + j * 16 + n16;
#pragma unroll
      for (int r = 0; r < 4; r++) {
        const float v = acc[i][j][r] * g.scale;
        if (obf) Cb[(row + r) * N + col] = f2bf(v);
        else     Cf[(row + r) * N + col] = v;
      }
    }
  }
}

// --------------------------------------------------- causal flash attention
// R13: qt-PAIRED blocks for guaranteed work balance. R12 showed the kernel is
// imbalance-bound: round-robin dispatch put blocks {c, c+256, c+512, c+768}
// (256 == 0 mod 32 -> ALL same qt) on one CU, so worst CUs ran 128 tiles while
// others ran 4 (57 us = 128 tiles at 2.2 tiles/us -- the per-CU rate itself is
// the best measured). Now each block processes qt = a AND qt = 31-a
// sequentially: exactly (a+1)+(32-a) = 33 tile-iters per block, for EVERY
// block, independent of dispatch order. Grid (16,16,2) = 512 blocks, 66
// tiles/CU everywhere. No split-K, no atomics: rsum is the full denominator,
// plain bf16 stores.
//
// Q pre-scaled by log2e/8 -> fixed-m softmax p = 2^s. S^T = K.Q^T via swapped
// operands; key-slot remap (PV contraction slot (kc,quad,t) -> key
// 32*kc + 16*(t>>2) + 4*quad + (t&3)) keeps the PV A-fragment lane-local.
// LDS: dense 64x64 XOR-swizzled tiles (conflict-free, verified 4.3M -> 0).
// REGISTER CLIFF: keep ~48-reg working set (R1/R4 spills); bounds (256,4).
#define SWZ(row, col) ((row) * 64 + ((col) ^ (((row) & 7) << 3)))

__global__ __launch_bounds__(256, 4) void flash_attn(
    const us* __restrict__ Q, const us* __restrict__ KV,
    us* __restrict__ O)
{
  __shared__ us Ks[64 * 64];      // [key][dim], swizzled
  __shared__ us Vt[64 * 64];      // [dim][slot], swizzled (slot = permuted key)

  const int a   = (int)blockIdx.x;       // 0..15
  const int h   = blockIdx.y;
  const int bb  = blockIdx.z;
  const int tid = threadIdx.x;
  const int lane = tid & 63;
  const int wave = tid >> 6;
  const int n16 = lane & 15;
  const int quad = lane >> 4;
  const long rowQ0 = (long)bb * SEQ;

  const f32x4 zero = {0.f, 0.f, 0.f, 0.f};

  const int kk_key = tid >> 3;
  const int kk_d8  = (tid & 7) * 8;
  const int vd  = tid & 63;
  const int vw  = tid >> 6;        // col block w: stores slots 8w..8w+7 (+32)
  const int vkb = vw * 8;

  const us* kgb = KV + (rowQ0 + kk_key) * 2048 + h * DH + kk_d8;
  // V source base at key 4w: lane (vd, w) loads keys {4w+r, 16+4w+r, 32+..., 48+...}
  const us* vgb = KV + (rowQ0 + vw * 4) * 2048 + KVP + h * DH + vd;

  uint4 kpre0, kpre1;
  us vraw[16];
  auto loadKV = [&](int kt) {
    const us* kg = kgb + (long)kt * (64 * 2048);
    kpre0 = *(const uint4*)kg;
    kpre1 = *(const uint4*)(kg + 32 * 2048);
    const us* vg = vgb + (long)kt * (64 * 2048);
#pragma unroll
    for (int r = 0; r < 4; r++) {
      vraw[r]      = vg[r * 2048];          // keys 4w + r        -> slots t=0..3 (kc=0)
      vraw[4 + r]  = vg[(16 + r) * 2048];   // keys 16 + 4w + r   -> slots t=4..7 (kc=0)
      vraw[8 + r]  = vg[(32 + r) * 2048];   // keys 32 + 4w + r   -> slots t=0..3 (kc=1)
      vraw[12 + r] = vg[(48 + r) * 2048];   // keys 48 + 4w + r   -> slots t=4..7 (kc=1)
    }
  };

  for (int ph = 0; ph < 2; ph++) {
    const int qt = ph ? (31 - a) : a;
    const int nt = qt + 1;
    const int qbase = qt * 64;

    bf16x8 aq[2];
    {
      const long gq = (rowQ0 + qbase + wave * 16 + n16) * DM + h * DH;
      aq[0] = *(const bf16x8*)(Q + gq + quad * 8);
      aq[1] = *(const bf16x8*)(Q + gq + 32 + quad * 8);
    }

    f32x4 oacc[4];
#pragma unroll
    for (int d = 0; d < 4; d++) oacc[d] = zero;
    float rsum = 0.f;              // row n16 partial sum

    loadKV(0);

    for (int kt = 0; kt < nt; kt++) {
      __syncthreads();
      *(uint4*)(Ks + SWZ(kk_key, kk_d8))      = kpre0;
      *(uint4*)(Ks + SWZ(kk_key + 32, kk_d8)) = kpre1;
      {
        uint4 p0, p1;
        p0.x = (unsigned)vraw[0]  | ((unsigned)vraw[1]  << 16);
        p0.y = (unsigned)vraw[2]  | ((unsigned)vraw[3]  << 16);
        p0.z = (unsigned)vraw[4]  | ((unsigned)vraw[5]  << 16);
        p0.w = (unsigned)vraw[6]  | ((unsigned)vraw[7]  << 16);
        p1.x = (unsigned)vraw[8]  | ((unsigned)vraw[9]  << 16);
        p1.y = (unsigned)vraw[10] | ((unsigned)vraw[11] << 16);
        p1.z = (unsigned)vraw[12] | ((unsigned)vraw[13] << 16);
        p1.w = (unsigned)vraw[14] | ((unsigned)vraw[15] << 16);
        *(uint4*)(Vt + SWZ(vd, vkb))      = p0;   // kc=0 slots, col block w
        *(uint4*)(Vt + SWZ(vd, vkb + 32)) = p1;   // kc=1 slots
      }
      __syncthreads();
      if (kt + 1 < nt) loadKV(kt + 1);

      // S^T = K Q^T: A = K-frag, B = aq. Lane holds S^T[key=j*16+quad*4+r][qrow=n16].
      f32x4 sv[4];
#pragma unroll
      for (int j = 0; j < 4; j++) {
        const bf16x8 ak0 = *(const bf16x8*)(Ks + SWZ(j * 16 + n16, quad * 8));
        const bf16x8 ak1 = *(const bf16x8*)(Ks + SWZ(j * 16 + n16, 32 + quad * 8));
        f32x4 s = zero;
        s = __builtin_amdgcn_mfma_f32_16x16x32_bf16(ak0, aq[0], s, 0, 0, 0);
        s = __builtin_amdgcn_mfma_f32_16x16x32_bf16(ak1, aq[1], s, 0, 0, 0);
        sv[j] = s;
      }

      // causal mask on the diagonal tile: key_local <= wave*16 + n16
      if (kt == qt) {
        const int qrl = wave * 16 + n16;
#pragma unroll
        for (int j = 0; j < 4; j++) {
          const int kl = j * 16 + quad * 4;
#pragma unroll
          for (int r = 0; r < 4; r++)
            sv[j][r] = (kl + r <= qrl) ? sv[j][r] : -1e30f;
        }
      }

      // p = 2^s, packed via v_cvt_pk_bf16_f32
      unsigned pep[4][2];
#pragma unroll
      for (int j = 0; j < 4; j++) {
        const float p0 = __builtin_amdgcn_exp2f(sv[j][0]);
        const float p1 = __builtin_amdgcn_exp2f(sv[j][1]);
        const float p2 = __builtin_amdgcn_exp2f(sv[j][2]);
        const float p3 = __builtin_amdgcn_exp2f(sv[j][3]);
        rsum += (p0 + p1) + (p2 + p3);
        pep[j][0] = cvtpk(p0, p1);
        pep[j][1] = cvtpk(p2, p3);
      }

      // O += P V  (A = lane-local P slots, B = V^T[dim][slot])
      __builtin_amdgcn_s_setprio(1);
#pragma unroll
      for (int kc = 0; kc < 2; kc++) {
        union { bf16x8 v; unsigned u[4]; } apu;
        apu.u[0] = pep[2 * kc][0];
        apu.u[1] = pep[2 * kc][1];
        apu.u[2] = pep[2 * kc + 1][0];
        apu.u[3] = pep[2 * kc + 1][1];
#pragma unroll
        for (int d = 0; d < 4; d++) {
          const bf16x8 bv = *(const bf16x8*)(Vt + SWZ(d * 16 + n16, kc * 32 + quad * 8));
          oacc[d] = __builtin_amdgcn_mfma_f32_16x16x32_bf16(apu.v, bv, oacc[d], 0, 0, 0);
        }
      }
      __builtin_amdgcn_s_setprio(0);
    }

    // full softmax denominator for q-row n16 (all keys live in this block)
    rsum += __shfl_xor(rsum, 16);
    rsum += __shfl_xor(rsum, 32);
    const float inv = 1.f / rsum;

    // oacc[d][r] belongs to q-row quad*4+r, dim d*16+n16; route inv via shfl.
    const long rw0 = rowQ0 + qbase + wave * 16;
#pragma unroll
    for (int r = 0; r < 4; r++) {
      const float invr = __shfl(inv, quad * 4 + r);
      us* dst = O + (rw0 + quad * 4 + r) * DM + h * DH + n16;
#pragma unroll
      for (int d = 0; d < 4; d++)
        dst[d * 16] = f2bf(oacc[d][r] * invr);
    }
    __syncthreads();   // Ks/Vt reuse fence before phase 2
  }
}

// ------------------------------------------------------------------------- host
extern "C" void kernel_launch(void* const* d_in, const int* in_sizes, int n_in,
                              void* d_out, int out_size, void* d_ws, size_t ws_size,
                              hipStream_t stream) {
  const void* x      = d_in[0];
  const void* Wdq    = d_in[1];
  const void* Wuq    = d_in[2];
  const void* qg     = d_in[3];
  const void* qb     = d_in[4];
  const void* Wdkv   = d_in[5];
  const void* Wukv   = d_in[6];
  const void* kvg    = d_in[7];
  const void* kvb    = d_in[8];
  const void* preqg  = d_in[9];
  const void* preqb  = d_in[10];
  const void* prekvg = d_in[11];
  const void* prekvb = d_in[12];
  const void* wo     = d_in[13];

  char* ws = (char*)d_ws;
  const long MB = 1 << 20;
  int* flag   = (int*)ws;
  us* wdq_t   = (us*)(ws + 1 * MB);
  us* wuq_t   = (us*)(ws + 2 * MB);
  us* wdkv_t  = (us*)(ws + 3 * MB);
  us* wukv_t  = (us*)(ws + 5 * MB);
  us* wo_c    = (us*)(ws + 9 * MB);
  us* xq      = (us*)(ws + 11 * MB);                       // 8 MB
  us* xkv     = (us*)(ws + 19 * MB);                       // 8 MB
  us* obuf    = (us*)(ws + 27 * MB);                       // 8 MB (flash output)
  us* tq_bf   = obuf;                                      // overlay: tq dead before flash writes obuf
  us* cq      = (us*)(ws + 35 * MB);                       // 4 MB
  us* qbuf    = (us*)(ws + 39 * MB);                       // 8 MB
  us* tkv_bf  = qbuf;                                      // overlay: dead before up-GEMM
  us* ckv     = (us*)(ws + 47 * MB);                       // 8 MB
  us* kv      = (us*)(ws + 55 * MB);                       // 16 MB -> 71 MB total

  // dtype: decide host-side from x's byte size; probe only if ambiguous
  {
    static int hflag;
    const long xb = (long)in_sizes[0];
    int known = -1;
    if (xb == (long)BATCH * SEQ * DM * 4) known = 0;       // f32
    else if (xb == (long)BATCH * SEQ * DM * 2) known = 1;  // bf16
    if (known >= 0) {
      hflag = known;
      hipMemcpyAsync(flag, &hflag, sizeof(int), hipMemcpyHostToDevice, stream);
    } else {
      detect_dtype<<<1, 256, 0, stream>>>((const us*)x, flag);
    }
  }

  // stage0: weights (5120 blocks) + ln_dual (4096)
  {
    TD t0 = { Wdq,  wdq_t,  1024,  512,  512, 1 };
    TD t1 = { Wuq,  wuq_t,   512, 1024,  512, 1 };
    TD t2 = { Wdkv, wdkv_t, 1024, 1024, 1024, 1 };
    TD t3 = { Wukv, wukv_t, 1024, 2048, 2048, 1 };
    TD t4 = { wo,   wo_c,   1024, 1024, 1024, 0 };
    stage0<<<9216, 256, 0, stream>>>(t0, t1, t2, t3, t4,
                                     x, preqg, preqb, prekvg, prekvb, xq, xkv, flag);
  }

  // down-projection pair (bf16 out)
  {
    GD g0 = { xq,  wdq_t,  tq_bf,   512, 1024, 2, 1.f, 1 };
    GD g1 = { xkv, wdkv_t, tkv_bf, 1024, 1024, 3, 1.f, 1 };
    gemm_mt<<<384, 256, 0, stream>>>(g0, g1, 128, flag);
  }

  ln_rows_pair<<<2 * NROWS, 256, 0, stream>>>(tq_bf, qg, qb, cq, tkv_bf, kvg, kvb, ckv, flag);

  // up-projection pair: Q scale = (1/8)*log2e for exp2-softmax
  {
    GD g0 = { cq,  wuq_t,  qbuf, 1024,  512, 3, 0.125f * 1.44269504f, 1 };
    GD g1 = { ckv, wukv_t, kv,   2048, 1024, 4, 1.f, 1 };
    gemm_mt<<<768, 256, 0, stream>>>(g0, g1, 256, flag);
  }

  // one block per (qt-pair, head, batch): every block = exactly 33 tile-iters
  flash_attn<<<dim3(16, NHEAD, BATCH), 256, 0, stream>>>(qbuf, kv, obuf);

  // out = O @ wo^T
  {
    GD g0 = { obuf, wo_c, d_out, 1024, 1024, 3, 1.f, 2 };
    gemm_mt<<<256, 256, 0, stream>>>(g0, g0, 256, flag);
  }
}

// Round 15
// 245.699 us; speedup vs baseline: 1.2142x; 1.0499x over previous
//
#include <hip/hip_runtime.h>
#include <hip/hip_bf16.h>

#define SEQ   2048
#define BATCH 2
#define NROWS 4096
#define DM    1024
#define NHEAD 16
#define DH    64
#define QP    512
#define KVP   1024

typedef unsigned short us;
typedef ushort4 us4;
using bf16x8 = __attribute__((ext_vector_type(8))) __bf16;
using f32x4  = __attribute__((ext_vector_type(4))) float;

__device__ __forceinline__ us f2bf(float f) {
  union { __hip_bfloat16 h; us u; } cv;
  cv.h = __float2bfloat16(f);
  return cv.u;
}
__device__ __forceinline__ float bf2f(us u) {
  union { unsigned int u32; float f; } cv;
  cv.u32 = ((unsigned int)u) << 16;
  return cv.f;
}
__device__ __forceinline__ float loadp(const void* p, long i, int isbf) {
  return isbf ? bf2f(((const us*)p)[i]) : ((const float*)p)[i];
}
__device__ __forceinline__ void async16(const void* g, void* l) {
  __builtin_amdgcn_global_load_lds((__attribute__((address_space(1))) void*)g,
                                   (__attribute__((address_space(3))) void*)l,
                                   16, 0, 0);
}
// pack two f32 -> packed bf16 pair (RNE), single VALU op (no builtin on gfx950)
__device__ __forceinline__ unsigned cvtpk(float lo, float hi) {
  unsigned r;
  asm("v_cvt_pk_bf16_f32 %0, %1, %2" : "=v"(r) : "v"(lo), "v"(hi));
  return r;
}

// ---------------------------------------------------------------- dtype probe
// (fallback only -- host decides from in_sizes[0] when unambiguous)
__global__ void detect_dtype(const us* __restrict__ xu, int* __restrict__ flag) {
  __shared__ int red[256];
  const int tid = threadIdx.x;
  int cnt = 0;
  for (int i = tid; i < 4096; i += 256) {
    const int e = (xu[i] >> 7) & 0xff;
    if (e == 0 || (e >= 100 && e <= 134)) cnt++;
  }
  red[tid] = cnt;
  __syncthreads();
  for (int s = 128; s; s >>= 1) {
    if (tid < s) red[tid] += red[tid + s];
    __syncthreads();
  }
  if (tid == 0) *flag = (red[0] >= 3900) ? 1 : 0;
}

// ------------- stage0: weight prep (transpose/cast) + dual-LN of x
struct TD { const void* in; us* out; int R, C, nt, trans; };

__global__ __launch_bounds__(256) void stage0(
    TD t0, TD t1, TD t2, TD t3, TD t4,
    const void* __restrict__ xin,                    // ln_dual (blocks 5120..9215)
    const void* __restrict__ g1, const void* __restrict__ b1,
    const void* __restrict__ g2, const void* __restrict__ b2,
    us* __restrict__ out1, us* __restrict__ out2,
    const int* __restrict__ flag)
{
  __shared__ us tile[32][33];
  __shared__ float red[8];
  __shared__ float musd[2];
  const int tid = threadIdx.x;
  const int isbf = *flag;
  int lin = blockIdx.x;

  if (lin < 5120) {                                  // ---- weight prep
    TD t = t0;
    if (lin >= t.nt) { lin -= t.nt; t = t1;
      if (lin >= t.nt) { lin -= t.nt; t = t2;
        if (lin >= t.nt) { lin -= t.nt; t = t3;
          if (lin >= t.nt) { lin -= t.nt; t = t4; } } } }
    const int ntx = t.C >> 5;
    const int by = lin / ntx, bx = lin - by * ntx;
    const int tx = tid & 31, ty = tid >> 5;
    const long r0 = (long)by * 32, c0 = (long)bx * 32;
    if (t.trans) {
#pragma unroll
      for (int i = 0; i < 32; i += 8)
        tile[ty + i][tx] = isbf ? ((const us*)t.in)[(r0 + ty + i) * t.C + c0 + tx]
                                : f2bf(((const float*)t.in)[(r0 + ty + i) * t.C + c0 + tx]);
      __syncthreads();
#pragma unroll
      for (int i = 0; i < 32; i += 8)
        t.out[(c0 + ty + i) * t.R + r0 + tx] = tile[tx][ty + i];
    } else {
#pragma unroll
      for (int i = 0; i < 32; i += 8)
        t.out[(r0 + ty + i) * t.C + c0 + tx] =
            isbf ? ((const us*)t.in)[(r0 + ty + i) * t.C + c0 + tx]
                 : f2bf(((const float*)t.in)[(r0 + ty + i) * t.C + c0 + tx]);
    }
    return;
  }
  // ---- dual LayerNorm row
  const long row = lin - 5120;
  float v[4];
  float s = 0.f, s2 = 0.f;
#pragma unroll
  for (int i = 0; i < 4; i++) {
    const long c = tid + i * 256;
    const float t = loadp(xin, row * 1024 + c, isbf);
    v[i] = t; s += t; s2 += t * t;
  }
#pragma unroll
  for (int off = 32; off > 0; off >>= 1) {
    s  += __shfl_down(s,  off);
    s2 += __shfl_down(s2, off);
  }
  const int wave = tid >> 6, lane = tid & 63;
  if (lane == 0) { red[wave] = s; red[4 + wave] = s2; }
  __syncthreads();
  if (tid == 0) {
    const float ts = red[0] + red[1] + red[2] + red[3];
    const float t2 = red[4] + red[5] + red[6] + red[7];
    const float mu = ts * (1.f / 1024.f);
    const float var = t2 * (1.f / 1024.f) - mu * mu;
    musd[0] = mu; musd[1] = rsqrtf(var + 1e-5f);
  }
  __syncthreads();
  const float mu = musd[0], rs = musd[1];
#pragma unroll
  for (int i = 0; i < 4; i++) {
    const long c = tid + i * 256;
    const float nrm = (v[i] - mu) * rs;
    out1[row * 1024 + c] = f2bf(nrm * loadp(g1, c, isbf) + loadp(b1, c, isbf));
    out2[row * 1024 + c] = f2bf(nrm * loadp(g2, c, isbf) + loadp(b2, c, isbf));
  }
}

// ------------------------------------------ paired row-LN (bf16 in -> bf16 out)
template<int C>
__device__ __forceinline__ void ln_body(const us* __restrict__ in,
                                        const void* __restrict__ g, const void* __restrict__ b,
                                        us* __restrict__ out, long row, int tid, int isbf) {
  constexpr int NP = C / 256;
  float v[NP];
  float s = 0.f, s2 = 0.f;
#pragma unroll
  for (int i = 0; i < NP; i++) {
    const float t = bf2f(in[row * C + tid + i * 256]);
    v[i] = t; s += t; s2 += t * t;
  }
#pragma unroll
  for (int off = 32; off > 0; off >>= 1) {
    s  += __shfl_down(s,  off);
    s2 += __shfl_down(s2, off);
  }
  __shared__ float red[8];
  __shared__ float musd[2];
  const int wave = tid >> 6, lane = tid & 63;
  if (lane == 0) { red[wave] = s; red[4 + wave] = s2; }
  __syncthreads();
  if (tid == 0) {
    const float ts = red[0] + red[1] + red[2] + red[3];
    const float t2 = red[4] + red[5] + red[6] + red[7];
    const float mu = ts * (1.f / C);
    const float var = t2 * (1.f / C) - mu * mu;
    musd[0] = mu; musd[1] = rsqrtf(var + 1e-5f);
  }
  __syncthreads();
  const float mu = musd[0], rs = musd[1];
#pragma unroll
  for (int i = 0; i < NP; i++) {
    const long c = tid + i * 256;
    out[row * C + c] = f2bf((v[i] - mu) * rs * loadp(g, c, isbf) + loadp(b, c, isbf));
  }
}

__global__ __launch_bounds__(256) void ln_rows_pair(
    const us* __restrict__ inq, const void* __restrict__ qg, const void* __restrict__ qb,
    us* __restrict__ outq,
    const us* __restrict__ inkv, const void* __restrict__ kvg, const void* __restrict__ kvb,
    us* __restrict__ outkv,
    const int* __restrict__ flag)
{
  const int isbf = *flag;
  if (blockIdx.x < NROWS)
    ln_body<512>(inq, qg, qb, outq, blockIdx.x, threadIdx.x, isbf);
  else
    ln_body<1024>(inkv, kvg, kvb, outkv, blockIdx.x - NROWS, threadIdx.x, isbf);
}

// ------------------------------------------------------------------ GEMM C = A @ B
// A [M,K] bf16, Bt [N,K] bf16 (= B^T), C [M,N]. 128x128 tile, BK=64 as two
// 32-wide LDS sub-slices (m97 layout preserved; barriers halved vs BK=32).
// omode: 0 = fp32 out, 1 = bf16 out, 2 = bf16 iff *flag.
// XCD swizzle (T1): consecutive logical tiles (sharing A-panels) pinned to one
// XCD's L2. All grids here are %8==0 -> simple bijective remap.
struct GD { const us* A; const us* Bt; void* C; int N, K, nxs; float scale; int omode; };

__global__ __launch_bounds__(256) void gemm_mt(GD g0, GD g1, int nb0,
                                               const int* __restrict__ flag) {
  __shared__ us As[2][128 * 32];
  __shared__ us Bs[2][128 * 32];
  GD g;
  int lin = blockIdx.x;
  {
    const int cpx = gridDim.x >> 3;        // gridDim.x % 8 == 0 for all launches
    lin = (lin & 7) * cpx + (lin >> 3);
  }
  if (lin < nb0) g = g0; else { g = g1; lin -= nb0; }
  const int by = lin >> g.nxs;
  const int bx = lin - (by << g.nxs);
  const int N = g.N, K = g.K;

  const int tid  = threadIdx.x;
  const int lane = tid & 63;
  const int wave = tid >> 6;
  const int n16  = lane & 15;
  const int quad = lane >> 4;
  const long m0 = (long)by * 128;
  const long n0 = (long)bx * 128;
  const int wm = (wave >> 1) * 64;
  const int wn = (wave & 1) * 64;

  const f32x4 zero = {0.f, 0.f, 0.f, 0.f};
  f32x4 acc[4][4];
#pragma unroll
  for (int i = 0; i < 4; i++)
#pragma unroll
    for (int j = 0; j < 4; j++) acc[i][j] = zero;

  const int srow = tid >> 2;
  const int scol = (tid & 3) * 8;
  const us* Ag0 = g.A  + (m0 + srow) * K + scol;
  const us* Ag1 = g.A  + (m0 + 64 + srow) * K + scol;
  const us* Bg0 = g.Bt + (n0 + srow) * K + scol;
  const us* Bg1 = g.Bt + (n0 + 64 + srow) * K + scol;
  const int lds_off = srow * 32 + scol;

  for (int k0 = 0; k0 < K; k0 += 64) {
#pragma unroll
    for (int s = 0; s < 2; s++) {
      const int ks = k0 + s * 32;
      async16(Ag0 + ks, As[s] + lds_off);
      async16(Ag1 + ks, As[s] + 2048 + lds_off);
      async16(Bg0 + ks, Bs[s] + lds_off);
      async16(Bg1 + ks, Bs[s] + 2048 + lds_off);
    }
    __syncthreads();
#pragma unroll
    for (int s = 0; s < 2; s++) {
      bf16x8 af[4], bfv[4];
#pragma unroll
      for (int i = 0; i < 4; i++)
        af[i] = *(const bf16x8*)(As[s] + (wm + i * 16 + n16) * 32 + quad * 8);
#pragma unroll
      for (int j = 0; j < 4; j++)
        bfv[j] = *(const bf16x8*)(Bs[s] + (wn + j * 16 + n16) * 32 + quad * 8);
#pragma unroll
      for (int i = 0; i < 4; i++)
#pragma unroll
        for (int j = 0; j < 4; j++)
          acc[i][j] = __builtin_amdgcn_mfma_f32_16x16x32_bf16(af[i], bfv[j], acc[i][j], 0, 0, 0);
    }
    __syncthreads();
  }

  const bool obf = (g.omode == 1) || (g.omode == 2 && *flag != 0);
  float* Cf = (float*)g.C;
  us* Cb = (us*)g.C;
#pragma unroll
  for (int i = 0; i < 4; i++) {
    const long row = m0 + wm + i * 16 + quad * 4;
#pragma unroll
    for (int j = 0; j < 4; j++) {
      const long col = n0 + wn + j * 16 + n16;
#pragma unroll
      for (int r = 0; r < 4; r++) {
        const float v = acc[i][j][r] * g.scale;
        if (obf) Cb[(row + r) * N + col] = f2bf(v);
        else     Cf[(row + r) * N + col] = v;
      }
    }
  }
}

// --------------------------------------------------- causal flash attention
// R15 = R14 resubmitted (R14 bench was an infra failure, no measurement).
// XCD-clustered head assignment: R13's counters showed FETCH 129 MB vs ~32 MB
// minimal -- round-robin dispatch spread the 16 blocks sharing one head's
// 512 KB KV slice over all 8 XCDs -> each private L2 re-fetched it (~8x KV
// duplication = the ~42 us of HBM time bounding the kernel). Flat 512-block
// grid, decoded so XCD g (= linear%8, round-robin assumption) owns 4 fixed
// (head,batch) combos: per-XCD working set 4*(512K KV + 256K Q) = 3 MB < 4 MB
// L2. qt-pair balance preserved: every block = exactly 33 tile-iters.
//
// No split-K, no atomics: rsum is the full denominator, plain bf16 stores.
// Q pre-scaled by log2e/8 -> fixed-m softmax p = 2^s. S^T = K.Q^T via swapped
// operands; key-slot remap (PV contraction slot (kc,quad,t) -> key
// 32*kc + 16*(t>>2) + 4*quad + (t&3)) keeps the PV A-fragment lane-local.
// LDS: dense 64x64 XOR-swizzled tiles (conflict-free, verified 4.3M -> 0).
// REGISTER CLIFF: keep ~48-64-reg working set (R1/R4 spills); bounds (256,4).
#define SWZ(row, col) ((row) * 64 + ((col) ^ (((row) & 7) << 3)))

__global__ __launch_bounds__(256, 4) void flash_attn(
    const us* __restrict__ Q, const us* __restrict__ KV,
    us* __restrict__ O)
{
  __shared__ us Ks[64 * 64];      // [key][dim], swizzled
  __shared__ us Vt[64 * 64];      // [dim][slot], swizzled (slot = permuted key)

  // XCD-clustered decode: l%8 = XCD (round-robin dispatch); each XCD owns
  // 4 (head,batch) combos so its L2 caches just those KV/Q slices.
  const int l   = (int)blockIdx.x;       // 0..511
  const int g8  = l & 7;
  const int j   = l >> 3;                // 0..63
  const int a   = j & 15;                // qt-pair index
  const int cq  = j >> 4;                // 0..3 combo-within-XCD
  const int combo = g8 * 4 + cq;         // 0..31
  const int h   = combo & 15;
  const int bb  = combo >> 4;

  const int tid = threadIdx.x;
  const int lane = tid & 63;
  const int wave = tid >> 6;
  const int n16 = lane & 15;
  const int quad = lane >> 4;
  const long rowQ0 = (long)bb * SEQ;

  const f32x4 zero = {0.f, 0.f, 0.f, 0.f};

  const int kk_key = tid >> 3;
  const int kk_d8  = (tid & 7) * 8;
  const int vd  = tid & 63;
  const int vw  = tid >> 6;        // col block w: stores slots 8w..8w+7 (+32)
  const int vkb = vw * 8;

  const us* kgb = KV + (rowQ0 + kk_key) * 2048 + h * DH + kk_d8;
  // V source base at key 4w: lane (vd, w) loads keys {4w+r, 16+4w+r, 32+..., 48+...}
  const us* vgb = KV + (rowQ0 + vw * 4) * 2048 + KVP + h * DH + vd;

  uint4 kpre0, kpre1;
  us vraw[16];
  auto loadKV = [&](int kt) {
    const us* kg = kgb + (long)kt * (64 * 2048);
    kpre0 = *(const uint4*)kg;
    kpre1 = *(const uint4*)(kg + 32 * 2048);
    const us* vg = vgb + (long)kt * (64 * 2048);
#pragma unroll
    for (int r = 0; r < 4; r++) {
      vraw[r]      = vg[r * 2048];          // keys 4w + r        -> slots t=0..3 (kc=0)
      vraw[4 + r]  = vg[(16 + r) * 2048];   // keys 16 + 4w + r   -> slots t=4..7 (kc=0)
      vraw[8 + r]  = vg[(32 + r) * 2048];   // keys 32 + 4w + r   -> slots t=0..3 (kc=1)
      vraw[12 + r] = vg[(48 + r) * 2048];   // keys 48 + 4w + r   -> slots t=4..7 (kc=1)
    }
  };

  for (int ph = 0; ph < 2; ph++) {
    const int qt = ph ? (31 - a) : a;
    const int nt = qt + 1;
    const int qbase = qt * 64;

    bf16x8 aq[2];
    {
      const long gq = (rowQ0 + qbase + wave * 16 + n16) * DM + h * DH;
      aq[0] = *(const bf16x8*)(Q + gq + quad * 8);
      aq[1] = *(const bf16x8*)(Q + gq + 32 + quad * 8);
    }

    f32x4 oacc[4];
#pragma unroll
    for (int d = 0; d < 4; d++) oacc[d] = zero;
    float rsum = 0.f;              // row n16 partial sum

    loadKV(0);

    for (int kt = 0; kt < nt; kt++) {
      __syncthreads();
      *(uint4*)(Ks + SWZ(kk_key, kk_d8))      = kpre0;
      *(uint4*)(Ks + SWZ(kk_key + 32, kk_d8)) = kpre1;
      {
        uint4 p0, p1;
        p0.x = (unsigned)vraw[0]  | ((unsigned)vraw[1]  << 16);
        p0.y = (unsigned)vraw[2]  | ((unsigned)vraw[3]  << 16);
        p0.z = (unsigned)vraw[4]  | ((unsigned)vraw[5]  << 16);
        p0.w = (unsigned)vraw[6]  | ((unsigned)vraw[7]  << 16);
        p1.x = (unsigned)vraw[8]  | ((unsigned)vraw[9]  << 16);
        p1.y = (unsigned)vraw[10] | ((unsigned)vraw[11] << 16);
        p1.z = (unsigned)vraw[12] | ((unsigned)vraw[13] << 16);
        p1.w = (unsigned)vraw[14] | ((unsigned)vraw[15] << 16);
        *(uint4*)(Vt + SWZ(vd, vkb))      = p0;   // kc=0 slots, col block w
        *(uint4*)(Vt + SWZ(vd, vkb + 32)) = p1;   // kc=1 slots
      }
      __syncthreads();
      if (kt + 1 < nt) loadKV(kt + 1);

      // S^T = K Q^T: A = K-frag, B = aq. Lane holds S^T[key=j*16+quad*4+r][qrow=n16].
      f32x4 sv[4];
#pragma unroll
      for (int j2 = 0; j2 < 4; j2++) {
        const bf16x8 ak0 = *(const bf16x8*)(Ks + SWZ(j2 * 16 + n16, quad * 8));
        const bf16x8 ak1 = *(const bf16x8*)(Ks + SWZ(j2 * 16 + n16, 32 + quad * 8));
        f32x4 s = zero;
        s = __builtin_amdgcn_mfma_f32_16x16x32_bf16(ak0, aq[0], s, 0, 0, 0);
        s = __builtin_amdgcn_mfma_f32_16x16x32_bf16(ak1, aq[1], s, 0, 0, 0);
        sv[j2] = s;
      }

      // causal mask on the diagonal tile: key_local <= wave*16 + n16
      if (kt == qt) {
        const int qrl = wave * 16 + n16;
#pragma unroll
        for (int j2 = 0; j2 < 4; j2++) {
          const int kl = j2 * 16 + quad * 4;
#pragma unroll
          for (int r = 0; r < 4; r++)
            sv[j2][r] = (kl + r <= qrl) ? sv[j2][r] : -1e30f;
        }
      }

      // p = 2^s, packed via v_cvt_pk_bf16_f32
      unsigned pep[4][2];
#pragma unroll
      for (int j2 = 0; j2 < 4; j2++) {
        const float p0 = __builtin_amdgcn_exp2f(sv[j2][0]);
        const float p1 = __builtin_amdgcn_exp2f(sv[j2][1]);
        const float p2 = __builtin_amdgcn_exp2f(sv[j2][2]);
        const float p3 = __builtin_amdgcn_exp2f(sv[j2][3]);
        rsum += (p0 + p1) + (p2 + p3);
        pep[j2][0] = cvtpk(p0, p1);
        pep[j2][1] = cvtpk(p2, p3);
      }

      // O += P V  (A = lane-local P slots, B = V^T[dim][slot])
      __builtin_amdgcn_s_setprio(1);
#pragma unroll
      for (int kc = 0; kc < 2; kc++) {
        union { bf16x8 v; unsigned u[4]; } apu;
        apu.u[0] = pep[2 * kc][0];
        apu.u[1] = pep[2 * kc][1];
        apu.u[2] = pep[2 * kc + 1][0];
        apu.u[3] = pep[2 * kc + 1][1];
#pragma unroll
        for (int d = 0; d < 4; d++) {
          const bf16x8 bv = *(const bf16x8*)(Vt + SWZ(d * 16 + n16, kc * 32 + quad * 8));
          oacc[d] = __builtin_amdgcn_mfma_f32_16x16x32_bf16(apu.v, bv, oacc[d], 0, 0, 0);
        }
      }
      __builtin_amdgcn_s_setprio(0);
    }

    // full softmax denominator for q-row n16 (all keys live in this block)
    rsum += __shfl_xor(rsum, 16);
    rsum += __shfl_xor(rsum, 32);
    const float inv = 1.f / rsum;

    // oacc[d][r] belongs to q-row quad*4+r, dim d*16+n16; route inv via shfl.
    const long rw0 = rowQ0 + qbase + wave * 16;
#pragma unroll
    for (int r = 0; r < 4; r++) {
      const float invr = __shfl(inv, quad * 4 + r);
      us* dst = O + (rw0 + quad * 4 + r) * DM + h * DH + n16;
#pragma unroll
      for (int d = 0; d < 4; d++)
        dst[d * 16] = f2bf(oacc[d][r] * invr);
    }
    __syncthreads();   // Ks/Vt reuse fence before phase 2
  }
}

// ------------------------------------------------------------------------- host
extern "C" void kernel_launch(void* const* d_in, const int* in_sizes, int n_in,
                              void* d_out, int out_size, void* d_ws, size_t ws_size,
                              hipStream_t stream) {
  const void* x      = d_in[0];
  const void* Wdq    = d_in[1];
  const void* Wuq    = d_in[2];
  const void* qg     = d_in[3];
  const void* qb     = d_in[4];
  const void* Wdkv   = d_in[5];
  const void* Wukv   = d_in[6];
  const void* kvg    = d_in[7];
  const void* kvb    = d_in[8];
  const void* preqg  = d_in[9];
  const void* preqb  = d_in[10];
  const void* prekvg = d_in[11];
  const void* prekvb = d_in[12];
  const void* wo     = d_in[13];

  char* ws = (char*)d_ws;
  const long MB = 1 << 20;
  int* flag   = (int*)ws;
  us* wdq_t   = (us*)(ws + 1 * MB);
  us* wuq_t   = (us*)(ws + 2 * MB);
  us* wdkv_t  = (us*)(ws + 3 * MB);
  us* wukv_t  = (us*)(ws + 5 * MB);
  us* wo_c    = (us*)(ws + 9 * MB);
  us* xq      = (us*)(ws + 11 * MB);                       // 8 MB
  us* xkv     = (us*)(ws + 19 * MB);                       // 8 MB
  us* obuf    = (us*)(ws + 27 * MB);                       // 8 MB (flash output)
  us* tq_bf   = obuf;                                      // overlay: tq dead before flash writes obuf
  us* cq      = (us*)(ws + 35 * MB);                       // 4 MB
  us* qbuf    = (us*)(ws + 39 * MB);                       // 8 MB
  us* tkv_bf  = qbuf;                                      // overlay: dead before up-GEMM
  us* ckv     = (us*)(ws + 47 * MB);                       // 8 MB
  us* kv      = (us*)(ws + 55 * MB);                       // 16 MB -> 71 MB total

  // dtype: decide host-side from x's byte size; probe only if ambiguous
  {
    static int hflag;
    const long xb = (long)in_sizes[0];
    int known = -1;
    if (xb == (long)BATCH * SEQ * DM * 4) known = 0;       // f32
    else if (xb == (long)BATCH * SEQ * DM * 2) known = 1;  // bf16
    if (known >= 0) {
      hflag = known;
      hipMemcpyAsync(flag, &hflag, sizeof(int), hipMemcpyHostToDevice, stream);
    } else {
      detect_dtype<<<1, 256, 0, stream>>>((const us*)x, flag);
    }
  }

  // stage0: weights (5120 blocks) + ln_dual (4096)
  {
    TD t0 = { Wdq,  wdq_t,  1024,  512,  512, 1 };
    TD t1 = { Wuq,  wuq_t,   512, 1024,  512, 1 };
    TD t2 = { Wdkv, wdkv_t, 1024, 1024, 1024, 1 };
    TD t3 = { Wukv, wukv_t, 1024, 2048, 2048, 1 };
    TD t4 = { wo,   wo_c,   1024, 1024, 1024, 0 };
    stage0<<<9216, 256, 0, stream>>>(t0, t1, t2, t3, t4,
                                     x, preqg, preqb, prekvg, prekvb, xq, xkv, flag);
  }

  // down-projection pair (bf16 out)
  {
    GD g0 = { xq,  wdq_t,  tq_bf,   512, 1024, 2, 1.f, 1 };
    GD g1 = { xkv, wdkv_t, tkv_bf, 1024, 1024, 3, 1.f, 1 };
    gemm_mt<<<384, 256, 0, stream>>>(g0, g1, 128, flag);
  }

  ln_rows_pair<<<2 * NROWS, 256, 0, stream>>>(tq_bf, qg, qb, cq, tkv_bf, kvg, kvb, ckv, flag);

  // up-projection pair: Q scale = (1/8)*log2e for exp2-softmax
  {
    GD g0 = { cq,  wuq_t,  qbuf, 1024,  512, 3, 0.125f * 1.44269504f, 1 };
    GD g1 = { ckv, wukv_t, kv,   2048, 1024, 4, 1.f, 1 };
    gemm_mt<<<768, 256, 0, stream>>>(g0, g1, 256, flag);
  }

  // flat 512-block grid, XCD-clustered (a, h, bb) decode in-kernel
  flash_attn<<<512, 256, 0, stream>>>(qbuf, kv, obuf);

  // out = O @ wo^T
  {
    GD g0 = { obuf, wo_c, d_out, 1024, 1024, 3, 1.f, 2 };
    gemm_mt<<<256, 256, 0, stream>>>(g0, g0, 256, flag);
  }
}